// Round 8
// baseline (862.838 us; speedup 1.0000x reference)
//
#include <hip/hip_runtime.h>

// ---------- constants ----------
#define DMODEL   1024
#define DINNER   2048
#define NHEADS   32
#define DHEAD    64
#define DSTATE   64
#define CONVDIM  2176
#define DINPROJ  4256
#define LSEQ     4096
#define BSZ      2
#define NCHUNK   16
#define CHUNK    256
#define NROWS    8192      // BSZ*LSEQ
#define NPAD     4352      // 34*128 = 17*256, padded in_proj rows
#define XT_P     264       // LDS transpose pitch (mult of 8, 2-way banks)
#define M_P      40        // M tile pitch

typedef __attribute__((ext_vector_type(8))) short  short8;
typedef __attribute__((ext_vector_type(4))) float  f32x4;
typedef __attribute__((ext_vector_type(4))) unsigned short us4;

__device__ __forceinline__ float bf2f(unsigned short u){
  return __uint_as_float(((unsigned int)u) << 16);
}
__device__ __forceinline__ unsigned short f2bf(float f){
  unsigned int i = __float_as_uint(f);
  i += 0x7fffu + ((i >> 16) & 1u);     // round-to-nearest-even
  return (unsigned short)(i >> 16);
}

// async global->LDS, 16B per lane (dest = wave-uniform base + lane*16)
__device__ __forceinline__ void gl_lds16(const void* g, void* l){
  __builtin_amdgcn_global_load_lds(
      (const __attribute__((address_space(1))) unsigned int*)g,
      (__attribute__((address_space(3))) unsigned int*)l, 16, 0, 0);
}

// ---------- cast f32 weights -> bf16 (optionally zero-pad extra rows) ----------
__global__ void cast_pad_kernel(const float* __restrict__ src, unsigned short* __restrict__ dst,
                                int rows_src, int cols, long long total){
  long long i = (long long)blockIdx.x * 256 + threadIdx.x;
  if (i >= total) return;
  long long r = i / cols;
  dst[i] = (r < rows_src) ? f2bf(src[i]) : (unsigned short)0;
}

// ---------- RMSNorm (f32 in -> bf16 out), row = 1024 ----------
__global__ void rmsnorm_kernel(const float* __restrict__ x, const float* __restrict__ w,
                               unsigned short* __restrict__ out){
  int r = blockIdx.x, t = threadIdx.x;
  const float* xr = x + (size_t)r * DMODEL;
  float v[4]; float s = 0.f;
#pragma unroll
  for (int i = 0; i < 4; ++i){ v[i] = xr[t + i*256]; s += v[i]*v[i]; }
  __shared__ float red[4];
  for (int off = 32; off; off >>= 1) s += __shfl_down(s, off, 64);
  if ((t & 63) == 0) red[t >> 6] = s;
  __syncthreads();
  s = red[0] + red[1] + red[2] + red[3];
  float sc = rsqrtf(s * (1.f/DMODEL) + 1e-5f);
#pragma unroll
  for (int i = 0; i < 4; ++i)
    out[(size_t)r*DMODEL + t + i*256] = f2bf(v[i]*sc*w[t + i*256]);
}

// ---------- 256x256 deep-pipelined bf16 MFMA GEMM (C = A.B^T), BK=32 ----------
// 8 waves (2Mx4N), per-wave 128x64 out. 4-buffer LDS ring (128 KiB), counted
// vmcnt (3 tiles in flight), XOR block-swizzled LDS via pre-swizzled global src.
// RACE FIX vs r7: per tile {vmcnt(N) -> bar1 -> STAGE(t+3) -> ds_read ->
// lgkmcnt(0) -> sched_barrier -> MFMA -> bar2}. bar2 + lgkm-drain guarantees all
// waves' reads of buf t&3 COMPLETE before any wave stages into it at t+1 (m152).
template<int EPI>
__launch_bounds__(512, 1)
__global__ void gemm256_bt(const unsigned short* __restrict__ A, const unsigned short* __restrict__ Bw,
                           void* __restrict__ Cout, const float* __restrict__ Cres,
                           int K, int Nstore, int nbx){
  __shared__ __align__(16) unsigned short As[4][256*32];
  __shared__ __align__(16) unsigned short Bs[4][256*32];
  const int nwg = gridDim.x;
  int id = blockIdx.x;
  if ((nwg & 7) == 0) id = (id & 7)*(nwg >> 3) + (id >> 3);   // bijective XCD swizzle
  const int m0 = (id / nbx) * 256, n0 = (id % nbx) * 256;
  const int tid = threadIdx.x, w = tid >> 6, lane = tid & 63;
  const int wr = w >> 2, wc = w & 3;
  const int nt = K >> 5;

  const int rQ = lane >> 2;                    // row-within-16 for staging
  const int bQ = (lane & 3) ^ (rQ & 3);        // logical k-block for pre-swizzled source
  const int koff = ((lane >> 4) ^ (lane & 3)) * 8;   // swizzled ds_read k-offset

  auto STAGE = [&](int bufi, int tile){
    const int k0 = tile << 5;
#pragma unroll
    for (int i = 0; i < 2; ++i){
      int r = w*32 + i*16 + rQ;
      gl_lds16(A  + (size_t)(m0 + r)*K + k0 + bQ*8, &As[bufi][(w*32 + i*16)*32]);
      gl_lds16(Bw + (size_t)(n0 + r)*K + k0 + bQ*8, &Bs[bufi][(w*32 + i*16)*32]);
    }
  };

  f32x4 acc[8][4] = {};
  STAGE(0, 0); STAGE(1, 1); STAGE(2, 2);       // 12 gl_lds/wave outstanding

  for (int t = 0; t < nt; ++t){
    if (t < nt-2)       asm volatile("s_waitcnt vmcnt(8)" ::: "memory");
    else if (t == nt-2) asm volatile("s_waitcnt vmcnt(4)" ::: "memory");
    else                asm volatile("s_waitcnt vmcnt(0)" ::: "memory");
    __builtin_amdgcn_s_barrier();              // bar1: tile t fully in LDS (all waves)
    asm volatile("" ::: "memory");
    if (t + 3 < nt) STAGE((t+3)&3, t+3);       // target buf freed by bar2 of t-1

    const unsigned short* Ab = As[t&3];
    const unsigned short* Bb = Bs[t&3];
    short8 af[8], bv[4];
#pragma unroll
    for (int mf = 0; mf < 8; ++mf)
      af[mf] = *(const short8*)&Ab[(wr*128 + mf*16 + (lane & 15))*32 + koff];
#pragma unroll
    for (int nf = 0; nf < 4; ++nf)
      bv[nf] = *(const short8*)&Bb[(wc*64 + nf*16 + (lane & 15))*32 + koff];
    asm volatile("s_waitcnt lgkmcnt(0)" ::: "memory");   // reads COMPLETE before bar2
    __builtin_amdgcn_sched_barrier(0);
    __builtin_amdgcn_s_setprio(1);
#pragma unroll
    for (int mf = 0; mf < 8; ++mf)
#pragma unroll
      for (int nf = 0; nf < 4; ++nf)
        acc[mf][nf] = __builtin_amdgcn_mfma_f32_16x16x32_bf16(af[mf], bv[nf], acc[mf][nf], 0, 0, 0);
    __builtin_amdgcn_s_setprio(0);
    asm volatile("" ::: "memory");
    __builtin_amdgcn_s_barrier();              // bar2: collective read-done fence
  }

#pragma unroll
  for (int mf = 0; mf < 8; ++mf){
#pragma unroll
    for (int nf = 0; nf < 4; ++nf){
      int col = n0 + wc*64 + nf*16 + (lane & 15);
      if (col < Nstore){
#pragma unroll
        for (int r = 0; r < 4; ++r){
          int row = m0 + wr*128 + mf*16 + (lane >> 4)*4 + r;
          if (EPI == 0)
            ((unsigned short*)Cout)[(size_t)row*Nstore + col] = f2bf(acc[mf][nf][r]);
          else
            ((float*)Cout)[(size_t)row*Nstore + col] =
                Cres[(size_t)row*Nstore + col] + acc[mf][nf][r];
        }
      }
    }
  }
}

// ---------- bf16 MFMA GEMM, 128x128 (m97 structure) — used for out_proj ----------
template<int EPI>
__launch_bounds__(256, 2)
__global__ void gemm_bt(const unsigned short* __restrict__ A, const unsigned short* __restrict__ Bw,
                        void* __restrict__ Cout, const float* __restrict__ Cres,
                        int K, int Nstore){
  __shared__ __align__(16) unsigned short As[128*64];
  __shared__ __align__(16) unsigned short Bs[128*64];
  const int m0 = blockIdx.y * 128, n0 = blockIdx.x * 128;
  const int t = threadIdx.x, w = t >> 6, lane = t & 63;
  const int wr = w >> 1, wc = w & 1;
  const int srow = lane >> 3;           // 0..7
  const int scol = (lane & 7) * 8;      // 0..56
  f32x4 acc[4][4] = {};

  for (int k0 = 0; k0 < K; k0 += 64){
#pragma unroll
    for (int it = 0; it < 4; ++it){
      int rr = (w*4 + it)*8 + srow;
      gl_lds16(A  + (size_t)(m0 + rr)*K + k0 + scol, &As[(w*4 + it)*512]);
      gl_lds16(Bw + (size_t)(n0 + rr)*K + k0 + scol, &Bs[(w*4 + it)*512]);
    }
    __syncthreads();
#pragma unroll
    for (int kk = 0; kk < 64; kk += 32){
      short8 af[4], bfr[4];
      int col = kk + (lane >> 4)*8;
#pragma unroll
      for (int m = 0; m < 4; ++m)
        af[m] = *(const short8*)&As[(wr*64 + m*16 + (lane & 15))*64 + col];
#pragma unroll
      for (int n = 0; n < 4; ++n)
        bfr[n] = *(const short8*)&Bs[(wc*64 + n*16 + (lane & 15))*64 + col];
#pragma unroll
      for (int m = 0; m < 4; ++m)
#pragma unroll
        for (int n = 0; n < 4; ++n)
          acc[m][n] = __builtin_amdgcn_mfma_f32_16x16x32_bf16(af[m], bfr[n], acc[m][n], 0, 0, 0);
    }
    __syncthreads();
  }

#pragma unroll
  for (int m = 0; m < 4; ++m){
#pragma unroll
    for (int n = 0; n < 4; ++n){
      int col = n0 + wc*64 + n*16 + (lane & 15);
      if (col < Nstore){
#pragma unroll
        for (int r = 0; r < 4; ++r){
          int row = m0 + wr*64 + m*16 + (lane >> 4)*4 + r;
          if (EPI == 0)
            ((unsigned short*)Cout)[(size_t)row*Nstore + col] = f2bf(acc[m][n][r]);
          else
            ((float*)Cout)[(size_t)row*Nstore + col] =
                Cres[(size_t)row*Nstore + col] + acc[m][n][r];
        }
      }
    }
  }
}

// ---------- causal conv1d (K=4) + silu, split into X / B / C ----------
__global__ void conv_silu_kernel(const unsigned short* __restrict__ zx,
                                 const float* __restrict__ cw, const float* __restrict__ cb,
                                 unsigned short* __restrict__ X, unsigned short* __restrict__ Bm,
                                 unsigned short* __restrict__ Cm){
  int c = blockIdx.x * 256 + threadIdx.x;
  if (c >= CONVDIM) return;
  int r = blockIdx.y;           // b*4096 + l
  int l = r & (LSEQ - 1);
  float acc = cb[c];
  float w0 = cw[c*4+0], w1 = cw[c*4+1], w2 = cw[c*4+2], w3 = cw[c*4+3];
#pragma unroll
  for (int i = 0; i < 4; ++i){
    int li = l - 3 + i;
    if (li >= 0){
      float v = bf2f(zx[(size_t)(r - 3 + i)*DINPROJ + DINNER + c]);
      float wi = (i==0)?w0:(i==1)?w1:(i==2)?w2:w3;
      acc += v * wi;
    }
  }
  float s = acc / (1.f + __expf(-acc));   // silu
  if (c < DINNER)            X[(size_t)r*DINNER + c]        = f2bf(s);
  else if (c < DINNER+DSTATE) Bm[(size_t)r*DSTATE + c-DINNER] = f2bf(s);
  else                        Cm[(size_t)r*DSTATE + c-DINNER-DSTATE] = f2bf(s);
}

// ---------- dt softplus + per-chunk inclusive cumsum of dA ----------
__global__ void dtscan_kernel(const unsigned short* __restrict__ zx, const float* __restrict__ dtb,
                              const float* __restrict__ A_log,
                              float* __restrict__ dt_sp, float* __restrict__ dAcs_g){
  const int z = blockIdx.x, hh = blockIdx.y, b = blockIdx.z;
  const int t = threadIdx.x;
  __shared__ float sdA[CHUNK];
  const float Ah = -__expf(A_log[hh]);
  size_t r = (size_t)b*LSEQ + z*CHUNK + t;
  float raw = bf2f(zx[r*DINPROJ + DINNER + CONVDIM + hh]) + dtb[hh];
  float dtv = raw > 20.f ? raw : log1pf(__expf(raw));
  sdA[t] = dtv * Ah;
  __syncthreads();
  for (int off = 1; off < CHUNK; off <<= 1){
    float v = (t >= off) ? sdA[t - off] : 0.f;
    __syncthreads();
    sdA[t] += v;
    __syncthreads();
  }
  size_t hb = (size_t)(b*NHEADS + hh);
  dt_sp[hb*LSEQ + z*CHUNK + t] = dtv;
  dAcs_g[(hb*NCHUNK + z)*CHUNK + t] = sdA[t];
}

// ---------- per-(b,chunk,head): states + within-chunk Yd, all MFMA ----------
__launch_bounds__(256, 2)
__global__ void chunk_main_kernel(const unsigned short* __restrict__ X,
                                  const unsigned short* __restrict__ Bm,
                                  const unsigned short* __restrict__ Cm,
                                  const float* __restrict__ dt_sp,
                                  const float* __restrict__ dAcs_g,
                                  float* __restrict__ states,
                                  unsigned short* __restrict__ Yb){
  const int z = blockIdx.x, hh = blockIdx.y, b = blockIdx.z;
  const int t = threadIdx.x, w = t >> 6, lane = t & 63;
  __shared__ __align__(16) unsigned short Xt[64 * XT_P];   // Xdt^T [p][l]
  __shared__ __align__(16) unsigned short U[64 * XT_P];    // union: Btdec -> M tiles -> Ystage
  __shared__ float sdA[CHUNK];
  __shared__ float sdt[CHUNK];

  const size_t row0 = (size_t)b*LSEQ + z*CHUNK;
  const size_t hb = (size_t)(b*NHEADS + hh);
  sdA[t] = dAcs_g[(hb*NCHUNK + z)*CHUNK + t];
  sdt[t] = dt_sp[hb*LSEQ + z*CHUNK + t];
  __syncthreads();
  const float total = sdA[CHUNK-1];

  // stage Xt[p][l] = X[l][p]*dt[l], U=Btdec[n][l] = B[l][n]*exp(total-sdA[l])
  for (int it = 0; it < 16; ++it){
    int l = it*16 + (t >> 4);
    int p4 = (t & 15) * 4;
    float dtl = sdt[l];
    float dec = __expf(total - sdA[l]);
    us4 xv = *(const us4*)(X  + (row0 + l)*DINNER + hh*DHEAD + p4);
    us4 bv = *(const us4*)(Bm + (row0 + l)*DSTATE + p4);
#pragma unroll
    for (int j = 0; j < 4; ++j){
      Xt[(p4 + j)*XT_P + l] = f2bf(bf2f(xv[j]) * dtl);
      U [(p4 + j)*XT_P + l] = f2bf(bf2f(bv[j]) * dec);
    }
  }
  __syncthreads();

  // ---- states: D[n][p] = sum_l Btdec[n][l] * Xt[p][l]; wave w owns n-tile w
  {
    f32x4 sacc[4] = {};
    for (int k2 = 0; k2 < 8; ++k2){
      int kc = k2*32 + (lane >> 4)*8;
      short8 a = *(const short8*)&U[(w*16 + (lane & 15))*XT_P + kc];
#pragma unroll
      for (int pt = 0; pt < 4; ++pt){
        short8 bfr = *(const short8*)&Xt[(pt*16 + (lane & 15))*XT_P + kc];
        sacc[pt] = __builtin_amdgcn_mfma_f32_16x16x32_bf16(a, bfr, sacc[pt], 0, 0, 0);
      }
    }
    float* sp = states + (((size_t)b*NCHUNK + z)*NHEADS + hh)*(DHEAD*DSTATE);
#pragma unroll
    for (int pt = 0; pt < 4; ++pt){
      int p = pt*16 + (lane & 15);
#pragma unroll
      for (int r = 0; r < 4; ++r){
        int n = w*16 + (lane >> 4)*4 + r;
        sp[p*DSTATE + n] = sacc[pt][r];
      }
    }
  }
  __syncthreads();   // Btdec dead; U becomes per-wave M tiles

  // ---- Yd: wave w owns l-tiles {w, w+4, w+8, w+12} (balanced triangle)
  unsigned short* Mw = U + w * (64 * M_P);
  short8 cfr[4][2];
#pragma unroll
  for (int lt = 0; lt < 4; ++lt){
    int lg = w + lt*4;
#pragma unroll
    for (int k2 = 0; k2 < 2; ++k2)
      cfr[lt][k2] = *(const short8*)(Cm + (row0 + lg*16 + (lane & 15))*DSTATE + k2*32 + (lane >> 4)*8);
  }
  f32x4 yacc[4][4] = {};
  for (int st = 0; st < 8; ++st){
    short8 gb[2][2];
#pragma unroll
    for (int ss = 0; ss < 2; ++ss)
#pragma unroll
      for (int k2 = 0; k2 < 2; ++k2)
        gb[ss][k2] = *(const short8*)(Bm + (row0 + st*32 + ss*16 + (lane & 15))*DSTATE + k2*32 + (lane >> 4)*8);
    short8 xb[4];
#pragma unroll
    for (int pt = 0; pt < 4; ++pt)
      xb[pt] = *(const short8*)&Xt[(pt*16 + (lane & 15))*XT_P + st*32 + (lane >> 4)*8];
#pragma unroll
    for (int lt = 0; lt < 4; ++lt){
      int lg = w + lt*4;
      if (st*32 > lg*16 + 15) continue;          // s-tile fully above diagonal
#pragma unroll
      for (int ss = 0; ss < 2; ++ss){
        f32x4 g = {};
        g = __builtin_amdgcn_mfma_f32_16x16x32_bf16(cfr[lt][0], gb[ss][0], g, 0, 0, 0);
        g = __builtin_amdgcn_mfma_f32_16x16x32_bf16(cfr[lt][1], gb[ss][1], g, 0, 0, 0);
        int s = st*32 + ss*16 + (lane & 15);
        float sdAs = sdA[s];
#pragma unroll
        for (int r = 0; r < 4; ++r){
          int l = lg*16 + (lane >> 4)*4 + r;
          float m = (s <= l) ? __expf(sdA[l] - sdAs) : 0.f;
          Mw[(lt*16 + (lane >> 4)*4 + r)*M_P + ss*16 + (lane & 15)] = f2bf(g[r] * m);
        }
      }
      short8 mf = *(const short8*)&Mw[(lt*16 + (lane & 15))*M_P + (lane >> 4)*8];
#pragma unroll
      for (int pt = 0; pt < 4; ++pt)
        yacc[lt][pt] = __builtin_amdgcn_mfma_f32_16x16x32_bf16(mf, xb[pt], yacc[lt][pt], 0, 0, 0);
    }
  }
  __syncthreads();   // M dead; U becomes Ystage

  // ---- stage Y (bf16, XOR-swizzled 8-elem blocks) and write out coalesced
  unsigned short* Yst = U + w * 4096;
#pragma unroll
  for (int lt = 0; lt < 4; ++lt)
#pragma unroll
    for (int pt = 0; pt < 4; ++pt)
#pragma unroll
      for (int r = 0; r < 4; ++r){
        int row = lt*16 + (lane >> 4)*4 + r;
        int c = pt*16 + (lane & 15);
        int cs = (c & 7) | ((((c >> 3) ^ (row & 7)) & 7) << 3);
        Yst[row*64 + cs] = f2bf(yacc[lt][pt][r]);
      }
  __syncthreads();
  {
    int ltl = lane >> 4, rr = lane & 15;
    int row = ltl*16 + rr;
    int lg = (w + ltl*4)*16 + rr;
    unsigned short* dst = Yb + (row0 + lg)*DINNER + hh*DHEAD;
#pragma unroll
    for (int k = 0; k < 8; ++k){
      short8 v = *(const short8*)&Yst[row*64 + ((k ^ (row & 7)) << 3)];
      *(short8*)(dst + k*8) = v;
    }
  }
}

// ---------- sequential inter-chunk recurrence; emits bf16 prev-states ----------
__launch_bounds__(64)
__global__ void state_recur_kernel(const float* __restrict__ states, const float* __restrict__ dAcs_g,
                                   unsigned short* __restrict__ prev_bf){
  const int hh = blockIdx.x, b = blockIdx.y, t = threadIdx.x;  // t = p
  float S[64];
#pragma unroll
  for (int j = 0; j < 64; ++j) S[j] = 0.f;
  for (int z = 0; z < NCHUNK; ++z){
    size_t idx = (((size_t)b*NCHUNK + z)*NHEADS + hh)*(DHEAD*DSTATE) + (size_t)t*DSTATE;
    float cd = __expf(dAcs_g[(((size_t)(b*NHEADS + hh))*NCHUNK + z)*CHUNK + CHUNK-1]);
    const float* st = states + idx;
    unsigned short* pb = prev_bf + idx;
#pragma unroll
    for (int j = 0; j < 64; ++j){
      pb[j] = f2bf(S[j]);
      S[j] = S[j]*cd + st[j];
    }
  }
}

// ---------- Yo = eA * (C . prev^T) via MFMA; combine Yd + Yo + D*X ----------
__launch_bounds__(256, 2)
__global__ void chunk_out_kernel(const unsigned short* __restrict__ X,
                                 const unsigned short* __restrict__ Cm,
                                 const float* __restrict__ dAcs_g, const unsigned short* __restrict__ prev_bf,
                                 const float* __restrict__ Dp, unsigned short* __restrict__ Yb){
  const int z = blockIdx.x, hh = blockIdx.y, b = blockIdx.z;
  const int t = threadIdx.x, w = t >> 6, lane = t & 63;
  __shared__ __align__(16) float Yo[4][64*64];
  __shared__ float sdA[CHUNK];
  const size_t row0 = (size_t)b*LSEQ + z*CHUNK;
  sdA[t] = dAcs_g[(((size_t)(b*NHEADS + hh))*NCHUNK + z)*CHUNK + t];
  __syncthreads();
  const unsigned short* pvb = prev_bf + (((size_t)b*NCHUNK + z)*NHEADS + hh)*(DHEAD*DSTATE);
  const float Dh = Dp[hh];

  f32x4 acc[4][4] = {};
#pragma unroll
  for (int k2 = 0; k2 < 2; ++k2){
    int kc = k2*32 + (lane >> 4)*8;
    short8 a[4], bfr[4];
#pragma unroll
    for (int lt = 0; lt < 4; ++lt)
      a[lt] = *(const short8*)(Cm + (row0 + w*64 + lt*16 + (lane & 15))*DSTATE + kc);
#pragma unroll
    for (int pt = 0; pt < 4; ++pt)
      bfr[pt] = *(const short8*)(pvb + (size_t)(pt*16 + (lane & 15))*DSTATE + kc);
#pragma unroll
    for (int lt = 0; lt < 4; ++lt)
#pragma unroll
      for (int pt = 0; pt < 4; ++pt)
        acc[lt][pt] = __builtin_amdgcn_mfma_f32_16x16x32_bf16(a[lt], bfr[pt], acc[lt][pt], 0, 0, 0);
  }

  // scale rows by eA and stage (f32, XOR-swizzled 4-elem blocks)
#pragma unroll
  for (int lt = 0; lt < 4; ++lt){
    float eA[4];
#pragma unroll
    for (int r = 0; r < 4; ++r)
      eA[r] = __expf(sdA[w*64 + lt*16 + (lane >> 4)*4 + r]);
#pragma unroll
    for (int pt = 0; pt < 4; ++pt){
      int c = pt*16 + (lane & 15);
#pragma unroll
      for (int r = 0; r < 4; ++r){
        int row = lt*16 + (lane >> 4)*4 + r;
        int blk = ((c >> 2) ^ (row & 15)) & 15;
        Yo[w][row*64 + (c & 3) + (blk << 2)] = acc[lt][pt][r] * eA[r];
      }
    }
  }
  __syncthreads();
  {
    int l = w*64 + lane;
    const unsigned short* xr = X + (row0 + l)*DINNER + hh*DHEAD;
    unsigned short* yr = Yb + (row0 + l)*DINNER + hh*DHEAD;
#pragma unroll
    for (int k = 0; k < 16; ++k){
      f32x4 v = *(const f32x4*)&Yo[w][lane*64 + (((k ^ (lane & 15)) & 15) << 2)];
      us4 yb = *(const us4*)(yr + k*4);
      us4 xv = *(const us4*)(xr + k*4);
      us4 o;
#pragma unroll
      for (int j = 0; j < 4; ++j)
        o[j] = f2bf(bf2f(yb[j]) + v[j] + Dh*bf2f(xv[j]));
      *(us4*)(yr + k*4) = o;
    }
  }
}

// ---------- gated RMSNorm: rmsnorm(y * silu(z)) * gw -> bf16 ----------
__global__ void gated_rmsnorm_kernel(const unsigned short* __restrict__ Yb,
                                     const unsigned short* __restrict__ zx,
                                     const float* __restrict__ gw, unsigned short* __restrict__ out){
  int r = blockIdx.x, t = threadIdx.x;
  float vals[8]; float s = 0.f;
#pragma unroll
  for (int i = 0; i < 8; ++i){
    int c = t + i*256;
    float y  = bf2f(Yb[(size_t)r*DINNER + c]);
    float zv = bf2f(zx[(size_t)r*DINPROJ + c]);
    float g  = y * (zv / (1.f + __expf(-zv)));
    vals[i] = g; s += g*g;
  }
  __shared__ float red[4];
  for (int off = 32; off; off >>= 1) s += __shfl_down(s, off, 64);
  if ((t & 63) == 0) red[t >> 6] = s;
  __syncthreads();
  s = red[0] + red[1] + red[2] + red[3];
  float sc = rsqrtf(s * (1.f/DINNER) + 1e-5f);
#pragma unroll
  for (int i = 0; i < 8; ++i)
    out[(size_t)r*DINNER + t + i*256] = f2bf(vals[i]*sc*gw[t + i*256]);
}

// ---------- launch ----------
extern "C" void kernel_launch(void* const* d_in, const int* in_sizes, int n_in,
                              void* d_out, int out_size, void* d_ws, size_t ws_size,
                              hipStream_t stream){
  const float* x      = (const float*)d_in[0];
  const float* in_w   = (const float*)d_in[1];
  const float* conv_w = (const float*)d_in[2];
  const float* conv_b = (const float*)d_in[3];
  const float* dt_b   = (const float*)d_in[4];
  const float* A_log  = (const float*)d_in[5];
  const float* Dp     = (const float*)d_in[6];
  const float* gnw    = (const float*)d_in[7];
  const float* out_w  = (const float*)d_in[8];
  const float* norm_w = (const float*)d_in[9];
  float* outp = (float*)d_out;

  const size_t NEEDED =
      (size_t)NROWS*DMODEL*2 + (size_t)NPAD*DMODEL*2 + (size_t)DMODEL*DINNER*2
    + (size_t)NROWS*DINPROJ*2 + (size_t)NROWS*DINNER*2 /*X*/ + (size_t)NROWS*DINNER*2 /*Yb*/
    + (size_t)NROWS*DSTATE*2*2 + (size_t)BSZ*NHEADS*LSEQ*4
    + (size_t)BSZ*NHEADS*NCHUNK*CHUNK*4
    + (size_t)BSZ*NCHUNK*NHEADS*DHEAD*DSTATE*4
    + (size_t)BSZ*NCHUNK*NHEADS*DHEAD*DSTATE*2   /* prev_bf */
    + 40*256;
  if (ws_size < NEEDED) return;   // clean fail signals ws too small

  char* p = (char*)d_ws;
  auto alloc = [&](size_t n){ char* r = p; p += (n + 255) & ~(size_t)255; return (void*)r; };
  unsigned short* h    = (unsigned short*)alloc((size_t)NROWS*DMODEL*2);
  unsigned short* wA   = (unsigned short*)alloc((size_t)NPAD*DMODEL*2);
  unsigned short* wO   = (unsigned short*)alloc((size_t)DMODEL*DINNER*2);
  unsigned short* zx   = (unsigned short*)alloc((size_t)NROWS*DINPROJ*2);
  unsigned short* X    = (unsigned short*)alloc((size_t)NROWS*DINNER*2);
  unsigned short* Yb   = (unsigned short*)alloc((size_t)NROWS*DINNER*2);
  unsigned short* Bm   = (unsigned short*)alloc((size_t)NROWS*DSTATE*2);
  unsigned short* Cm   = (unsigned short*)alloc((size_t)NROWS*DSTATE*2);
  float* dtbuf  = (float*)alloc((size_t)BSZ*NHEADS*LSEQ*4);
  float* dAcs   = (float*)alloc((size_t)BSZ*NHEADS*NCHUNK*CHUNK*4);
  float* states = (float*)alloc((size_t)BSZ*NCHUNK*NHEADS*DHEAD*DSTATE*4);
  unsigned short* prev_bf = (unsigned short*)alloc((size_t)BSZ*NCHUNK*NHEADS*DHEAD*DSTATE*2);
  unsigned short* yn = X;   // alias: X dead after chunk_out; yn born at gated_rmsnorm

  for (int layer = 0; layer < 2; ++layer){
    const float* xprev = (layer == 0) ? x : outp;
    float* xnext = outp;

    cast_pad_kernel<<<(NPAD*DMODEL + 255)/256, 256, 0, stream>>>(
        in_w + (size_t)layer*DINPROJ*DMODEL, wA, DINPROJ, DMODEL, (long long)NPAD*DMODEL);
    rmsnorm_kernel<<<NROWS, 256, 0, stream>>>(xprev, norm_w + layer*DMODEL, h);
    gemm256_bt<0><<<dim3((NROWS/256)*(NPAD/256)), 512, 0, stream>>>(
        h, wA, (void*)zx, nullptr, DMODEL, DINPROJ, NPAD/256);
    conv_silu_kernel<<<dim3((CONVDIM + 255)/256, NROWS), 256, 0, stream>>>(
        zx, conv_w + (size_t)layer*CONVDIM*4, conv_b + layer*CONVDIM, X, Bm, Cm);
    dtscan_kernel<<<dim3(NCHUNK, NHEADS, BSZ), 256, 0, stream>>>(
        zx, dt_b + layer*NHEADS, A_log + layer*NHEADS, dtbuf, dAcs);
    chunk_main_kernel<<<dim3(NCHUNK, NHEADS, BSZ), 256, 0, stream>>>(
        X, Bm, Cm, dtbuf, dAcs, states, Yb);
    state_recur_kernel<<<dim3(NHEADS, BSZ), 64, 0, stream>>>(states, dAcs, prev_bf);
    chunk_out_kernel<<<dim3(NCHUNK, NHEADS, BSZ), 256, 0, stream>>>(
        X, Cm, dAcs, prev_bf, Dp + layer*NHEADS, Yb);
    gated_rmsnorm_kernel<<<NROWS, 256, 0, stream>>>(Yb, zx, gnw + layer*DINNER, yn);
    cast_pad_kernel<<<(DMODEL*DINNER + 255)/256, 256, 0, stream>>>(
        out_w + (size_t)layer*DMODEL*DINNER, wO, DMODEL, DINNER, (long long)DMODEL*DINNER);
    gemm_bt<1><<<dim3(DMODEL/128, NROWS/128), 256, 0, stream>>>(
        yn, wO, (void*)xnext, xprev, DINNER, DMODEL);
  }
  (void)in_sizes; (void)n_in; (void)out_size;
}

// Round 9
// 764.392 us; speedup vs baseline: 1.1288x; 1.1288x over previous
//
#include <hip/hip_runtime.h>

// ---------- constants ----------
#define DMODEL   1024
#define DINNER   2048
#define NHEADS   32
#define DHEAD    64
#define DSTATE   64
#define CONVDIM  2176
#define DINPROJ  4256
#define LSEQ     4096
#define BSZ      2
#define NCHUNK   16
#define CHUNK    256
#define NROWS    8192      // BSZ*LSEQ
#define NPAD     4352      // 34*128, padded in_proj rows
#define XT_P     264       // LDS transpose pitch (mult of 8, 2-way banks)
#define M_P      40        // M tile pitch

typedef __attribute__((ext_vector_type(8))) short  short8;
typedef __attribute__((ext_vector_type(4))) float  f32x4;
typedef __attribute__((ext_vector_type(4))) unsigned short us4;

__device__ __forceinline__ float bf2f(unsigned short u){
  return __uint_as_float(((unsigned int)u) << 16);
}
__device__ __forceinline__ unsigned short f2bf(float f){
  unsigned int i = __float_as_uint(f);
  i += 0x7fffu + ((i >> 16) & 1u);     // round-to-nearest-even
  return (unsigned short)(i >> 16);
}

// async global->LDS, 16B per lane (dest = wave-uniform base + lane*16)
__device__ __forceinline__ void gl_lds16(const void* g, void* l){
  __builtin_amdgcn_global_load_lds(
      (const __attribute__((address_space(1))) unsigned int*)g,
      (__attribute__((address_space(3))) unsigned int*)l, 16, 0, 0);
}

// ---------- cast f32 weights -> bf16 (optionally zero-pad extra rows) ----------
__global__ void cast_pad_kernel(const float* __restrict__ src, unsigned short* __restrict__ dst,
                                int rows_src, int cols, long long total){
  long long i = (long long)blockIdx.x * 256 + threadIdx.x;
  if (i >= total) return;
  long long r = i / cols;
  dst[i] = (r < rows_src) ? f2bf(src[i]) : (unsigned short)0;
}

// ---------- RMSNorm (f32 in -> bf16 out), row = 1024 ----------
__global__ void rmsnorm_kernel(const float* __restrict__ x, const float* __restrict__ w,
                               unsigned short* __restrict__ out){
  int r = blockIdx.x, t = threadIdx.x;
  const float* xr = x + (size_t)r * DMODEL;
  float v[4]; float s = 0.f;
#pragma unroll
  for (int i = 0; i < 4; ++i){ v[i] = xr[t + i*256]; s += v[i]*v[i]; }
  __shared__ float red[4];
  for (int off = 32; off; off >>= 1) s += __shfl_down(s, off, 64);
  if ((t & 63) == 0) red[t >> 6] = s;
  __syncthreads();
  s = red[0] + red[1] + red[2] + red[3];
  float sc = rsqrtf(s * (1.f/DMODEL) + 1e-5f);
#pragma unroll
  for (int i = 0; i < 4; ++i)
    out[(size_t)r*DMODEL + t + i*256] = f2bf(v[i]*sc*w[t + i*256]);
}

// ---------- bf16 MFMA GEMM, C[i,j] = sum_k A[i,k]*B[j,k]  (both K-contiguous) ----------
// 128x128 tile, BK=64, 4 waves (2x2), 16x16x32 MFMA. m97 structure.
// launch_bounds (256,3): 3 blocks/CU (12 waves) for cross-block overlap of the
// barrier drain (m114); LDS 32KB x3 = 96KB <= 160, VGPR 76 -> no spill at cap 170.
template<int EPI>
__launch_bounds__(256, 3)
__global__ void gemm_bt(const unsigned short* __restrict__ A, const unsigned short* __restrict__ Bw,
                        void* __restrict__ Cout, const float* __restrict__ Cres,
                        int K, int Nstore){
  __shared__ __align__(16) unsigned short As[128*64];
  __shared__ __align__(16) unsigned short Bs[128*64];
  const int m0 = blockIdx.y * 128, n0 = blockIdx.x * 128;
  const int t = threadIdx.x, w = t >> 6, lane = t & 63;
  const int wr = w >> 1, wc = w & 1;
  const int srow = lane >> 3;           // 0..7
  const int scol = (lane & 7) * 8;      // 0..56
  f32x4 acc[4][4] = {};

  for (int k0 = 0; k0 < K; k0 += 64){
#pragma unroll
    for (int it = 0; it < 4; ++it){
      int rr = (w*4 + it)*8 + srow;
      gl_lds16(A  + (size_t)(m0 + rr)*K + k0 + scol, &As[(w*4 + it)*512]);
      gl_lds16(Bw + (size_t)(n0 + rr)*K + k0 + scol, &Bs[(w*4 + it)*512]);
    }
    __syncthreads();
#pragma unroll
    for (int kk = 0; kk < 64; kk += 32){
      short8 af[4], bfr[4];
      int col = kk + (lane >> 4)*8;
#pragma unroll
      for (int m = 0; m < 4; ++m)
        af[m] = *(const short8*)&As[(wr*64 + m*16 + (lane & 15))*64 + col];
#pragma unroll
      for (int n = 0; n < 4; ++n)
        bfr[n] = *(const short8*)&Bs[(wc*64 + n*16 + (lane & 15))*64 + col];
#pragma unroll
      for (int m = 0; m < 4; ++m)
#pragma unroll
        for (int n = 0; n < 4; ++n)
          acc[m][n] = __builtin_amdgcn_mfma_f32_16x16x32_bf16(af[m], bfr[n], acc[m][n], 0, 0, 0);
    }
    __syncthreads();
  }

#pragma unroll
  for (int m = 0; m < 4; ++m){
#pragma unroll
    for (int n = 0; n < 4; ++n){
      int col = n0 + wc*64 + n*16 + (lane & 15);
      if (col < Nstore){
#pragma unroll
        for (int r = 0; r < 4; ++r){
          int row = m0 + wr*64 + m*16 + (lane >> 4)*4 + r;
          if (EPI == 0)
            ((unsigned short*)Cout)[(size_t)row*Nstore + col] = f2bf(acc[m][n][r]);
          else
            ((float*)Cout)[(size_t)row*Nstore + col] =
                Cres[(size_t)row*Nstore + col] + acc[m][n][r];
        }
      }
    }
  }
}

// ---------- causal conv1d (K=4) + silu, split into X / B / C ----------
__global__ void conv_silu_kernel(const unsigned short* __restrict__ zx,
                                 const float* __restrict__ cw, const float* __restrict__ cb,
                                 unsigned short* __restrict__ X, unsigned short* __restrict__ Bm,
                                 unsigned short* __restrict__ Cm){
  int c = blockIdx.x * 256 + threadIdx.x;
  if (c >= CONVDIM) return;
  int r = blockIdx.y;           // b*4096 + l
  int l = r & (LSEQ - 1);
  float acc = cb[c];
  float w0 = cw[c*4+0], w1 = cw[c*4+1], w2 = cw[c*4+2], w3 = cw[c*4+3];
#pragma unroll
  for (int i = 0; i < 4; ++i){
    int li = l - 3 + i;
    if (li >= 0){
      float v = bf2f(zx[(size_t)(r - 3 + i)*DINPROJ + DINNER + c]);
      float wi = (i==0)?w0:(i==1)?w1:(i==2)?w2:w3;
      acc += v * wi;
    }
  }
  float s = acc / (1.f + __expf(-acc));   // silu
  if (c < DINNER)            X[(size_t)r*DINNER + c]        = f2bf(s);
  else if (c < DINNER+DSTATE) Bm[(size_t)r*DSTATE + c-DINNER] = f2bf(s);
  else                        Cm[(size_t)r*DSTATE + c-DINNER-DSTATE] = f2bf(s);
}

// ---------- dt softplus + per-chunk inclusive cumsum of dA ----------
__global__ void dtscan_kernel(const unsigned short* __restrict__ zx, const float* __restrict__ dtb,
                              const float* __restrict__ A_log,
                              float* __restrict__ dt_sp, float* __restrict__ dAcs_g){
  const int z = blockIdx.x, hh = blockIdx.y, b = blockIdx.z;
  const int t = threadIdx.x;
  __shared__ float sdA[CHUNK];
  const float Ah = -__expf(A_log[hh]);
  size_t r = (size_t)b*LSEQ + z*CHUNK + t;
  float raw = bf2f(zx[r*DINPROJ + DINNER + CONVDIM + hh]) + dtb[hh];
  float dtv = raw > 20.f ? raw : log1pf(__expf(raw));
  sdA[t] = dtv * Ah;
  __syncthreads();
  for (int off = 1; off < CHUNK; off <<= 1){
    float v = (t >= off) ? sdA[t - off] : 0.f;
    __syncthreads();
    sdA[t] += v;
    __syncthreads();
  }
  size_t hb = (size_t)(b*NHEADS + hh);
  dt_sp[hb*LSEQ + z*CHUNK + t] = dtv;
  dAcs_g[(hb*NCHUNK + z)*CHUNK + t] = sdA[t];
}

// ---------- per-(b,chunk,head): states + within-chunk Yd, all MFMA ----------
__launch_bounds__(256, 2)
__global__ void chunk_main_kernel(const unsigned short* __restrict__ X,
                                  const unsigned short* __restrict__ Bm,
                                  const unsigned short* __restrict__ Cm,
                                  const float* __restrict__ dt_sp,
                                  const float* __restrict__ dAcs_g,
                                  float* __restrict__ states,
                                  unsigned short* __restrict__ Yb){
  const int z = blockIdx.x, hh = blockIdx.y, b = blockIdx.z;
  const int t = threadIdx.x, w = t >> 6, lane = t & 63;
  __shared__ __align__(16) unsigned short Xt[64 * XT_P];   // Xdt^T [p][l]
  __shared__ __align__(16) unsigned short U[64 * XT_P];    // union: Btdec -> M tiles -> Ystage
  __shared__ float sdA[CHUNK];
  __shared__ float sdt[CHUNK];

  const size_t row0 = (size_t)b*LSEQ + z*CHUNK;
  const size_t hb = (size_t)(b*NHEADS + hh);
  sdA[t] = dAcs_g[(hb*NCHUNK + z)*CHUNK + t];
  sdt[t] = dt_sp[hb*LSEQ + z*CHUNK + t];
  __syncthreads();
  const float total = sdA[CHUNK-1];

  // stage Xt[p][l] = X[l][p]*dt[l], U=Btdec[n][l] = B[l][n]*exp(total-sdA[l])
  for (int it = 0; it < 16; ++it){
    int l = it*16 + (t >> 4);
    int p4 = (t & 15) * 4;
    float dtl = sdt[l];
    float dec = __expf(total - sdA[l]);
    us4 xv = *(const us4*)(X  + (row0 + l)*DINNER + hh*DHEAD + p4);
    us4 bv = *(const us4*)(Bm + (row0 + l)*DSTATE + p4);
#pragma unroll
    for (int j = 0; j < 4; ++j){
      Xt[(p4 + j)*XT_P + l] = f2bf(bf2f(xv[j]) * dtl);
      U [(p4 + j)*XT_P + l] = f2bf(bf2f(bv[j]) * dec);
    }
  }
  __syncthreads();

  // ---- states: D[n][p] = sum_l Btdec[n][l] * Xt[p][l]; wave w owns n-tile w
  {
    f32x4 sacc[4] = {};
    for (int k2 = 0; k2 < 8; ++k2){
      int kc = k2*32 + (lane >> 4)*8;
      short8 a = *(const short8*)&U[(w*16 + (lane & 15))*XT_P + kc];
#pragma unroll
      for (int pt = 0; pt < 4; ++pt){
        short8 bfr = *(const short8*)&Xt[(pt*16 + (lane & 15))*XT_P + kc];
        sacc[pt] = __builtin_amdgcn_mfma_f32_16x16x32_bf16(a, bfr, sacc[pt], 0, 0, 0);
      }
    }
    float* sp = states + (((size_t)b*NCHUNK + z)*NHEADS + hh)*(DHEAD*DSTATE);
#pragma unroll
    for (int pt = 0; pt < 4; ++pt){
      int p = pt*16 + (lane & 15);
#pragma unroll
      for (int r = 0; r < 4; ++r){
        int n = w*16 + (lane >> 4)*4 + r;
        sp[p*DSTATE + n] = sacc[pt][r];
      }
    }
  }
  __syncthreads();   // Btdec dead; U becomes per-wave M tiles

  // ---- Yd: wave w owns l-tiles {w, w+4, w+8, w+12} (balanced triangle)
  unsigned short* Mw = U + w * (64 * M_P);
  short8 cfr[4][2];
#pragma unroll
  for (int lt = 0; lt < 4; ++lt){
    int lg = w + lt*4;
#pragma unroll
    for (int k2 = 0; k2 < 2; ++k2)
      cfr[lt][k2] = *(const short8*)(Cm + (row0 + lg*16 + (lane & 15))*DSTATE + k2*32 + (lane >> 4)*8);
  }
  f32x4 yacc[4][4] = {};
  for (int st = 0; st < 8; ++st){
    short8 gb[2][2];
#pragma unroll
    for (int ss = 0; ss < 2; ++ss)
#pragma unroll
      for (int k2 = 0; k2 < 2; ++k2)
        gb[ss][k2] = *(const short8*)(Bm + (row0 + st*32 + ss*16 + (lane & 15))*DSTATE + k2*32 + (lane >> 4)*8);
    short8 xb[4];
#pragma unroll
    for (int pt = 0; pt < 4; ++pt)
      xb[pt] = *(const short8*)&Xt[(pt*16 + (lane & 15))*XT_P + st*32 + (lane >> 4)*8];
#pragma unroll
    for (int lt = 0; lt < 4; ++lt){
      int lg = w + lt*4;
      if (st*32 > lg*16 + 15) continue;          // s-tile fully above diagonal
#pragma unroll
      for (int ss = 0; ss < 2; ++ss){
        f32x4 g = {};
        g = __builtin_amdgcn_mfma_f32_16x16x32_bf16(cfr[lt][0], gb[ss][0], g, 0, 0, 0);
        g = __builtin_amdgcn_mfma_f32_16x16x32_bf16(cfr[lt][1], gb[ss][1], g, 0, 0, 0);
        int s = st*32 + ss*16 + (lane & 15);
        float sdAs = sdA[s];
#pragma unroll
        for (int r = 0; r < 4; ++r){
          int l = lg*16 + (lane >> 4)*4 + r;
          float m = (s <= l) ? __expf(sdA[l] - sdAs) : 0.f;
          Mw[(lt*16 + (lane >> 4)*4 + r)*M_P + ss*16 + (lane & 15)] = f2bf(g[r] * m);
        }
      }
      short8 mf = *(const short8*)&Mw[(lt*16 + (lane & 15))*M_P + (lane >> 4)*8];
#pragma unroll
      for (int pt = 0; pt < 4; ++pt)
        yacc[lt][pt] = __builtin_amdgcn_mfma_f32_16x16x32_bf16(mf, xb[pt], yacc[lt][pt], 0, 0, 0);
    }
  }
  __syncthreads();   // M dead; U becomes Ystage

  // ---- stage Y (bf16, XOR-swizzled 8-elem blocks) and write out coalesced
  unsigned short* Yst = U + w * 4096;
#pragma unroll
  for (int lt = 0; lt < 4; ++lt)
#pragma unroll
    for (int pt = 0; pt < 4; ++pt)
#pragma unroll
      for (int r = 0; r < 4; ++r){
        int row = lt*16 + (lane >> 4)*4 + r;
        int c = pt*16 + (lane & 15);
        int cs = (c & 7) | ((((c >> 3) ^ (row & 7)) & 7) << 3);
        Yst[row*64 + cs] = f2bf(yacc[lt][pt][r]);
      }
  __syncthreads();
  {
    int ltl = lane >> 4, rr = lane & 15;
    int row = ltl*16 + rr;
    int lg = (w + ltl*4)*16 + rr;
    unsigned short* dst = Yb + (row0 + lg)*DINNER + hh*DHEAD;
#pragma unroll
    for (int k = 0; k < 8; ++k){
      short8 v = *(const short8*)&Yst[row*64 + ((k ^ (row & 7)) << 3)];
      *(short8*)(dst + k*8) = v;
    }
  }
}

// ---------- sequential inter-chunk recurrence; emits bf16 prev-states ----------
// Coalesced: 256 threads, thread t owns flat columns {t, t+256, ...} of the
// 4096-elem (p,n) state matrix -> every load/store is a contiguous 1KB/wave.
__launch_bounds__(256)
__global__ void state_recur_kernel(const float* __restrict__ states, const float* __restrict__ dAcs_g,
                                   unsigned short* __restrict__ prev_bf){
  const int hh = blockIdx.x, b = blockIdx.y, t = threadIdx.x;
  float S[16];
#pragma unroll
  for (int k = 0; k < 16; ++k) S[k] = 0.f;
  for (int z = 0; z < NCHUNK; ++z){
    size_t base = (((size_t)b*NCHUNK + z)*NHEADS + hh)*(DHEAD*DSTATE);
    float cd = __expf(dAcs_g[(((size_t)(b*NHEADS + hh))*NCHUNK + z)*CHUNK + CHUNK-1]);
#pragma unroll
    for (int k = 0; k < 16; ++k){
      size_t idx = base + (size_t)k*256 + t;
      float st = states[idx];
      prev_bf[idx] = f2bf(S[k]);
      S[k] = S[k]*cd + st;
    }
  }
}

// ---------- Yo = eA * (C . prev^T) via MFMA; combine Yd + Yo + D*X ----------
__launch_bounds__(256, 2)
__global__ void chunk_out_kernel(const unsigned short* __restrict__ X,
                                 const unsigned short* __restrict__ Cm,
                                 const float* __restrict__ dAcs_g, const unsigned short* __restrict__ prev_bf,
                                 const float* __restrict__ Dp, unsigned short* __restrict__ Yb){
  const int z = blockIdx.x, hh = blockIdx.y, b = blockIdx.z;
  const int t = threadIdx.x, w = t >> 6, lane = t & 63;
  __shared__ __align__(16) float Yo[4][64*64];
  __shared__ float sdA[CHUNK];
  const size_t row0 = (size_t)b*LSEQ + z*CHUNK;
  sdA[t] = dAcs_g[(((size_t)(b*NHEADS + hh))*NCHUNK + z)*CHUNK + t];
  __syncthreads();
  const unsigned short* pvb = prev_bf + (((size_t)b*NCHUNK + z)*NHEADS + hh)*(DHEAD*DSTATE);
  const float Dh = Dp[hh];

  f32x4 acc[4][4] = {};
#pragma unroll
  for (int k2 = 0; k2 < 2; ++k2){
    int kc = k2*32 + (lane >> 4)*8;
    short8 a[4], bfr[4];
#pragma unroll
    for (int lt = 0; lt < 4; ++lt)
      a[lt] = *(const short8*)(Cm + (row0 + w*64 + lt*16 + (lane & 15))*DSTATE + kc);
#pragma unroll
    for (int pt = 0; pt < 4; ++pt)
      bfr[pt] = *(const short8*)(pvb + (size_t)(pt*16 + (lane & 15))*DSTATE + kc);
#pragma unroll
    for (int lt = 0; lt < 4; ++lt)
#pragma unroll
      for (int pt = 0; pt < 4; ++pt)
        acc[lt][pt] = __builtin_amdgcn_mfma_f32_16x16x32_bf16(a[lt], bfr[pt], acc[lt][pt], 0, 0, 0);
  }

  // scale rows by eA and stage (f32, XOR-swizzled 4-elem blocks)
#pragma unroll
  for (int lt = 0; lt < 4; ++lt){
    float eA[4];
#pragma unroll
    for (int r = 0; r < 4; ++r)
      eA[r] = __expf(sdA[w*64 + lt*16 + (lane >> 4)*4 + r]);
#pragma unroll
    for (int pt = 0; pt < 4; ++pt){
      int c = pt*16 + (lane & 15);
#pragma unroll
      for (int r = 0; r < 4; ++r){
        int row = lt*16 + (lane >> 4)*4 + r;
        int blk = ((c >> 2) ^ (row & 15)) & 15;
        Yo[w][row*64 + (c & 3) + (blk << 2)] = acc[lt][pt][r] * eA[r];
      }
    }
  }
  __syncthreads();
  {
    int l = w*64 + lane;
    const unsigned short* xr = X + (row0 + l)*DINNER + hh*DHEAD;
    unsigned short* yr = Yb + (row0 + l)*DINNER + hh*DHEAD;
#pragma unroll
    for (int k = 0; k < 16; ++k){
      f32x4 v = *(const f32x4*)&Yo[w][lane*64 + (((k ^ (lane & 15)) & 15) << 2)];
      us4 yb = *(const us4*)(yr + k*4);
      us4 xv = *(const us4*)(xr + k*4);
      us4 o;
#pragma unroll
      for (int j = 0; j < 4; ++j)
        o[j] = f2bf(bf2f(yb[j]) + v[j] + Dh*bf2f(xv[j]));
      *(us4*)(yr + k*4) = o;
    }
  }
}

// ---------- gated RMSNorm: rmsnorm(y * silu(z)) * gw -> bf16 ----------
__global__ void gated_rmsnorm_kernel(const unsigned short* __restrict__ Yb,
                                     const unsigned short* __restrict__ zx,
                                     const float* __restrict__ gw, unsigned short* __restrict__ out){
  int r = blockIdx.x, t = threadIdx.x;
  float vals[8]; float s = 0.f;
#pragma unroll
  for (int i = 0; i < 8; ++i){
    int c = t + i*256;
    float y  = bf2f(Yb[(size_t)r*DINNER + c]);
    float zv = bf2f(zx[(size_t)r*DINPROJ + c]);
    float g  = y * (zv / (1.f + __expf(-zv)));
    vals[i] = g; s += g*g;
  }
  __shared__ float red[4];
  for (int off = 32; off; off >>= 1) s += __shfl_down(s, off, 64);
  if ((t & 63) == 0) red[t >> 6] = s;
  __syncthreads();
  s = red[0] + red[1] + red[2] + red[3];
  float sc = rsqrtf(s * (1.f/DINNER) + 1e-5f);
#pragma unroll
  for (int i = 0; i < 8; ++i)
    out[(size_t)r*DINNER + t + i*256] = f2bf(vals[i]*sc*gw[t + i*256]);
}

// ---------- launch ----------
extern "C" void kernel_launch(void* const* d_in, const int* in_sizes, int n_in,
                              void* d_out, int out_size, void* d_ws, size_t ws_size,
                              hipStream_t stream){
  const float* x      = (const float*)d_in[0];
  const float* in_w   = (const float*)d_in[1];
  const float* conv_w = (const float*)d_in[2];
  const float* conv_b = (const float*)d_in[3];
  const float* dt_b   = (const float*)d_in[4];
  const float* A_log  = (const float*)d_in[5];
  const float* Dp     = (const float*)d_in[6];
  const float* gnw    = (const float*)d_in[7];
  const float* out_w  = (const float*)d_in[8];
  const float* norm_w = (const float*)d_in[9];
  float* outp = (float*)d_out;

  const size_t NEEDED =
      (size_t)NROWS*DMODEL*2 + (size_t)NPAD*DMODEL*2 + (size_t)DMODEL*DINNER*2
    + (size_t)NROWS*DINPROJ*2 + (size_t)NROWS*DINNER*2 /*X*/ + (size_t)NROWS*DINNER*2 /*Yb*/
    + (size_t)NROWS*DSTATE*2*2 + (size_t)BSZ*NHEADS*LSEQ*4
    + (size_t)BSZ*NHEADS*NCHUNK*CHUNK*4
    + (size_t)BSZ*NCHUNK*NHEADS*DHEAD*DSTATE*4
    + (size_t)BSZ*NCHUNK*NHEADS*DHEAD*DSTATE*2   /* prev_bf */
    + 40*256;
  if (ws_size < NEEDED) return;   // clean fail signals ws too small

  char* p = (char*)d_ws;
  auto alloc = [&](size_t n){ char* r = p; p += (n + 255) & ~(size_t)255; return (void*)r; };
  unsigned short* h    = (unsigned short*)alloc((size_t)NROWS*DMODEL*2);
  unsigned short* wA   = (unsigned short*)alloc((size_t)NPAD*DMODEL*2);
  unsigned short* wO   = (unsigned short*)alloc((size_t)DMODEL*DINNER*2);
  unsigned short* zx   = (unsigned short*)alloc((size_t)NROWS*DINPROJ*2);
  unsigned short* X    = (unsigned short*)alloc((size_t)NROWS*DINNER*2);
  unsigned short* Yb   = (unsigned short*)alloc((size_t)NROWS*DINNER*2);
  unsigned short* Bm   = (unsigned short*)alloc((size_t)NROWS*DSTATE*2);
  unsigned short* Cm   = (unsigned short*)alloc((size_t)NROWS*DSTATE*2);
  float* dtbuf  = (float*)alloc((size_t)BSZ*NHEADS*LSEQ*4);
  float* dAcs   = (float*)alloc((size_t)BSZ*NHEADS*NCHUNK*CHUNK*4);
  float* states = (float*)alloc((size_t)BSZ*NCHUNK*NHEADS*DHEAD*DSTATE*4);
  unsigned short* prev_bf = (unsigned short*)alloc((size_t)BSZ*NCHUNK*NHEADS*DHEAD*DSTATE*2);
  unsigned short* yn = X;   // alias: X dead after chunk_out; yn born at gated_rmsnorm

  for (int layer = 0; layer < 2; ++layer){
    const float* xprev = (layer == 0) ? x : outp;
    float* xnext = outp;

    cast_pad_kernel<<<(NPAD*DMODEL + 255)/256, 256, 0, stream>>>(
        in_w + (size_t)layer*DINPROJ*DMODEL, wA, DINPROJ, DMODEL, (long long)NPAD*DMODEL);
    rmsnorm_kernel<<<NROWS, 256, 0, stream>>>(xprev, norm_w + layer*DMODEL, h);
    gemm_bt<0><<<dim3(NPAD/128, NROWS/128), 256, 0, stream>>>(
        h, wA, (void*)zx, nullptr, DMODEL, DINPROJ);
    conv_silu_kernel<<<dim3((CONVDIM + 255)/256, NROWS), 256, 0, stream>>>(
        zx, conv_w + (size_t)layer*CONVDIM*4, conv_b + layer*CONVDIM, X, Bm, Cm);
    dtscan_kernel<<<dim3(NCHUNK, NHEADS, BSZ), 256, 0, stream>>>(
        zx, dt_b + layer*NHEADS, A_log + layer*NHEADS, dtbuf, dAcs);
    chunk_main_kernel<<<dim3(NCHUNK, NHEADS, BSZ), 256, 0, stream>>>(
        X, Bm, Cm, dtbuf, dAcs, states, Yb);
    state_recur_kernel<<<dim3(NHEADS, BSZ), 256, 0, stream>>>(states, dAcs, prev_bf);
    chunk_out_kernel<<<dim3(NCHUNK, NHEADS, BSZ), 256, 0, stream>>>(
        X, Cm, dAcs, prev_bf, Dp + layer*NHEADS, Yb);
    gated_rmsnorm_kernel<<<NROWS, 256, 0, stream>>>(Yb, zx, gnw + layer*DINNER, yn);
    cast_pad_kernel<<<(DMODEL*DINNER + 255)/256, 256, 0, stream>>>(
        out_w + (size_t)layer*DMODEL*DINNER, wO, DMODEL, DINNER, (long long)DMODEL*DINNER);
    gemm_bt<1><<<dim3(DMODEL/128, NROWS/128), 256, 0, stream>>>(
        yn, wO, (void*)xnext, xprev, DINNER, DMODEL);
  }
  (void)in_sizes; (void)n_in; (void)out_size;
}

// Round 10
// 732.618 us; speedup vs baseline: 1.1777x; 1.0434x over previous
//
#include <hip/hip_runtime.h>

// ---------- constants ----------
#define DMODEL   1024
#define DINNER   2048
#define NHEADS   32
#define DHEAD    64
#define DSTATE   64
#define CONVDIM  2176
#define DINPROJ  4256
#define LSEQ     4096
#define BSZ      2
#define NCHUNK   16
#define CHUNK    256
#define NROWS    8192      // BSZ*LSEQ
#define NPAD     4352      // 34*128, padded in_proj rows
#define XT_P     264       // LDS transpose pitch (mult of 8, 2-way banks)
#define M_P      40        // M tile pitch

typedef __attribute__((ext_vector_type(8))) short  short8;
typedef __attribute__((ext_vector_type(4))) float  f32x4;
typedef __attribute__((ext_vector_type(4))) unsigned short us4;

__device__ __forceinline__ float bf2f(unsigned short u){
  return __uint_as_float(((unsigned int)u) << 16);
}
__device__ __forceinline__ unsigned short f2bf(float f){
  unsigned int i = __float_as_uint(f);
  i += 0x7fffu + ((i >> 16) & 1u);     // round-to-nearest-even
  return (unsigned short)(i >> 16);
}

// async global->LDS, 16B per lane (dest = wave-uniform base + lane*16)
__device__ __forceinline__ void gl_lds16(const void* g, void* l){
  __builtin_amdgcn_global_load_lds(
      (const __attribute__((address_space(1))) unsigned int*)g,
      (__attribute__((address_space(3))) unsigned int*)l, 16, 0, 0);
}

// ---------- cast f32 weights -> bf16 (optionally zero-pad extra rows) ----------
__global__ void cast_pad_kernel(const float* __restrict__ src, unsigned short* __restrict__ dst,
                                int rows_src, int cols, long long total){
  long long i = (long long)blockIdx.x * 256 + threadIdx.x;
  if (i >= total) return;
  long long r = i / cols;
  dst[i] = (r < rows_src) ? f2bf(src[i]) : (unsigned short)0;
}

// ---------- RMSNorm (f32 in -> bf16 out), row = 1024 ----------
__global__ void rmsnorm_kernel(const float* __restrict__ x, const float* __restrict__ w,
                               unsigned short* __restrict__ out){
  int r = blockIdx.x, t = threadIdx.x;
  const float* xr = x + (size_t)r * DMODEL;
  float v[4]; float s = 0.f;
#pragma unroll
  for (int i = 0; i < 4; ++i){ v[i] = xr[t + i*256]; s += v[i]*v[i]; }
  __shared__ float red[4];
  for (int off = 32; off; off >>= 1) s += __shfl_down(s, off, 64);
  if ((t & 63) == 0) red[t >> 6] = s;
  __syncthreads();
  s = red[0] + red[1] + red[2] + red[3];
  float sc = rsqrtf(s * (1.f/DMODEL) + 1e-5f);
#pragma unroll
  for (int i = 0; i < 4; ++i)
    out[(size_t)r*DMODEL + t + i*256] = f2bf(v[i]*sc*w[t + i*256]);
}

// ---------- bf16 MFMA GEMM, C[i,j] = sum_k A[i,k]*B[j,k]  (both K-contiguous) ----------
// 128x128 tile, BK=64, 4 waves (2x2), 16x16x32 MFMA. m97 structure.
template<int EPI>
__launch_bounds__(256, 3)
__global__ void gemm_bt(const unsigned short* __restrict__ A, const unsigned short* __restrict__ Bw,
                        void* __restrict__ Cout, const float* __restrict__ Cres,
                        int K, int Nstore){
  __shared__ __align__(16) unsigned short As[128*64];
  __shared__ __align__(16) unsigned short Bs[128*64];
  const int m0 = blockIdx.y * 128, n0 = blockIdx.x * 128;
  const int t = threadIdx.x, w = t >> 6, lane = t & 63;
  const int wr = w >> 1, wc = w & 1;
  const int srow = lane >> 3;           // 0..7
  const int scol = (lane & 7) * 8;      // 0..56
  f32x4 acc[4][4] = {};

  for (int k0 = 0; k0 < K; k0 += 64){
#pragma unroll
    for (int it = 0; it < 4; ++it){
      int rr = (w*4 + it)*8 + srow;
      gl_lds16(A  + (size_t)(m0 + rr)*K + k0 + scol, &As[(w*4 + it)*512]);
      gl_lds16(Bw + (size_t)(n0 + rr)*K + k0 + scol, &Bs[(w*4 + it)*512]);
    }
    __syncthreads();
#pragma unroll
    for (int kk = 0; kk < 64; kk += 32){
      short8 af[4], bfr[4];
      int col = kk + (lane >> 4)*8;
#pragma unroll
      for (int m = 0; m < 4; ++m)
        af[m] = *(const short8*)&As[(wr*64 + m*16 + (lane & 15))*64 + col];
#pragma unroll
      for (int n = 0; n < 4; ++n)
        bfr[n] = *(const short8*)&Bs[(wc*64 + n*16 + (lane & 15))*64 + col];
#pragma unroll
      for (int m = 0; m < 4; ++m)
#pragma unroll
        for (int n = 0; n < 4; ++n)
          acc[m][n] = __builtin_amdgcn_mfma_f32_16x16x32_bf16(af[m], bfr[n], acc[m][n], 0, 0, 0);
    }
    __syncthreads();
  }

#pragma unroll
  for (int m = 0; m < 4; ++m){
#pragma unroll
    for (int n = 0; n < 4; ++n){
      int col = n0 + wc*64 + n*16 + (lane & 15);
      if (col < Nstore){
#pragma unroll
        for (int r = 0; r < 4; ++r){
          int row = m0 + wr*64 + m*16 + (lane >> 4)*4 + r;
          if (EPI == 0)
            ((unsigned short*)Cout)[(size_t)row*Nstore + col] = f2bf(acc[m][n][r]);
          else
            ((float*)Cout)[(size_t)row*Nstore + col] =
                Cres[(size_t)row*Nstore + col] + acc[m][n][r];
        }
      }
    }
  }
}

// ---------- causal conv1d (K=4) + silu, 8 channels/thread, rolling taps ----------
// Each thread: channel octet oc (8 ch) x 64 rows. 16B vector loads/stores; reads
// each zx element once (vs 4x before); 136 blocks (vs 73k).
__global__ void conv_silu_kernel(const unsigned short* __restrict__ zx,
                                 const float* __restrict__ cw, const float* __restrict__ cb,
                                 unsigned short* __restrict__ X, unsigned short* __restrict__ Bm,
                                 unsigned short* __restrict__ Cm){
  int gid = blockIdx.x*256 + threadIdx.x;
  if (gid >= (CONVDIM/8)*(NROWS/64)) return;
  const int oc = gid % (CONVDIM/8);
  const int rb = gid / (CONVDIM/8);
  const int c = oc*8;
  const size_t r0 = (size_t)rb*64;
  const int l0 = (int)(r0 & (LSEQ-1));
  float w[4][8], bias[8];
#pragma unroll
  for (int j = 0; j < 8; ++j){
    bias[j] = cb[c+j];
#pragma unroll
    for (int i = 0; i < 4; ++i) w[i][j] = cw[(c+j)*4 + i];
  }
  const unsigned short* src = zx + DINNER + c;
  float p[3][8];
#pragma unroll
  for (int i = 0; i < 3; ++i){
    if (l0 - 3 + i >= 0){
      short8 v = *(const short8*)(src + (r0 - 3 + i)*DINPROJ);
#pragma unroll
      for (int j = 0; j < 8; ++j) p[i][j] = bf2f((unsigned short)v[j]);
    } else {
#pragma unroll
      for (int j = 0; j < 8; ++j) p[i][j] = 0.f;
    }
  }
  for (int it = 0; it < 64; ++it){
    const size_t r = r0 + it;
    short8 v = *(const short8*)(src + r*DINPROJ);
    float cur[8];
    short8 ov;
#pragma unroll
    for (int j = 0; j < 8; ++j){
      cur[j] = bf2f((unsigned short)v[j]);
      float a = bias[j] + w[0][j]*p[0][j] + w[1][j]*p[1][j] + w[2][j]*p[2][j] + w[3][j]*cur[j];
      float s = a / (1.f + __expf(-a));
      ov[j] = (short)f2bf(s);
    }
    if (c < DINNER)             *(short8*)(X  + r*DINNER + c) = ov;
    else if (c < DINNER+DSTATE) *(short8*)(Bm + r*DSTATE + (c-DINNER)) = ov;
    else                        *(short8*)(Cm + r*DSTATE + (c-DINNER-DSTATE)) = ov;
#pragma unroll
    for (int j = 0; j < 8; ++j){ p[0][j]=p[1][j]; p[1][j]=p[2][j]; p[2][j]=cur[j]; }
  }
}

// ---------- dt softplus + per-chunk inclusive cumsum of dA ----------
__global__ void dtscan_kernel(const unsigned short* __restrict__ zx, const float* __restrict__ dtb,
                              const float* __restrict__ A_log,
                              float* __restrict__ dt_sp, float* __restrict__ dAcs_g){
  const int z = blockIdx.x, hh = blockIdx.y, b = blockIdx.z;
  const int t = threadIdx.x;
  __shared__ float sdA[CHUNK];
  const float Ah = -__expf(A_log[hh]);
  size_t r = (size_t)b*LSEQ + z*CHUNK + t;
  float raw = bf2f(zx[r*DINPROJ + DINNER + CONVDIM + hh]) + dtb[hh];
  float dtv = raw > 20.f ? raw : log1pf(__expf(raw));
  sdA[t] = dtv * Ah;
  __syncthreads();
  for (int off = 1; off < CHUNK; off <<= 1){
    float v = (t >= off) ? sdA[t - off] : 0.f;
    __syncthreads();
    sdA[t] += v;
    __syncthreads();
  }
  size_t hb = (size_t)(b*NHEADS + hh);
  dt_sp[hb*LSEQ + z*CHUNK + t] = dtv;
  dAcs_g[(hb*NCHUNK + z)*CHUNK + t] = sdA[t];
}

// ---------- per-(b,chunk,head): states + within-chunk Yd, all MFMA ----------
__launch_bounds__(256, 2)
__global__ void chunk_main_kernel(const unsigned short* __restrict__ X,
                                  const unsigned short* __restrict__ Bm,
                                  const unsigned short* __restrict__ Cm,
                                  const float* __restrict__ dt_sp,
                                  const float* __restrict__ dAcs_g,
                                  float* __restrict__ states,
                                  unsigned short* __restrict__ Yb){
  const int z = blockIdx.x, hh = blockIdx.y, b = blockIdx.z;
  const int t = threadIdx.x, w = t >> 6, lane = t & 63;
  __shared__ __align__(16) unsigned short Xt[64 * XT_P];   // Xdt^T [p][l]
  __shared__ __align__(16) unsigned short U[64 * XT_P];    // union: Btdec -> M tiles -> Ystage
  __shared__ float sdA[CHUNK];
  __shared__ float sdt[CHUNK];

  const size_t row0 = (size_t)b*LSEQ + z*CHUNK;
  const size_t hb = (size_t)(b*NHEADS + hh);
  sdA[t] = dAcs_g[(hb*NCHUNK + z)*CHUNK + t];
  sdt[t] = dt_sp[hb*LSEQ + z*CHUNK + t];
  __syncthreads();
  const float total = sdA[CHUNK-1];

  // stage Xt[p][l] = X[l][p]*dt[l], U=Btdec[n][l] = B[l][n]*exp(total-sdA[l])
  for (int it = 0; it < 16; ++it){
    int l = it*16 + (t >> 4);
    int p4 = (t & 15) * 4;
    float dtl = sdt[l];
    float dec = __expf(total - sdA[l]);
    us4 xv = *(const us4*)(X  + (row0 + l)*DINNER + hh*DHEAD + p4);
    us4 bv = *(const us4*)(Bm + (row0 + l)*DSTATE + p4);
#pragma unroll
    for (int j = 0; j < 4; ++j){
      Xt[(p4 + j)*XT_P + l] = f2bf(bf2f(xv[j]) * dtl);
      U [(p4 + j)*XT_P + l] = f2bf(bf2f(bv[j]) * dec);
    }
  }
  __syncthreads();

  // ---- states: D[n][p] = sum_l Btdec[n][l] * Xt[p][l]; wave w owns n-tile w
  {
    f32x4 sacc[4] = {};
    for (int k2 = 0; k2 < 8; ++k2){
      int kc = k2*32 + (lane >> 4)*8;
      short8 a = *(const short8*)&U[(w*16 + (lane & 15))*XT_P + kc];
#pragma unroll
      for (int pt = 0; pt < 4; ++pt){
        short8 bfr = *(const short8*)&Xt[(pt*16 + (lane & 15))*XT_P + kc];
        sacc[pt] = __builtin_amdgcn_mfma_f32_16x16x32_bf16(a, bfr, sacc[pt], 0, 0, 0);
      }
    }
    float* sp = states + (((size_t)b*NCHUNK + z)*NHEADS + hh)*(DHEAD*DSTATE);
#pragma unroll
    for (int pt = 0; pt < 4; ++pt){
      int p = pt*16 + (lane & 15);
#pragma unroll
      for (int r = 0; r < 4; ++r){
        int n = w*16 + (lane >> 4)*4 + r;
        sp[p*DSTATE + n] = sacc[pt][r];
      }
    }
  }
  __syncthreads();   // Btdec dead; U becomes per-wave M tiles

  // ---- Yd: wave w owns l-tiles {w, w+4, w+8, w+12} (balanced triangle)
  unsigned short* Mw = U + w * (64 * M_P);
  short8 cfr[4][2];
#pragma unroll
  for (int lt = 0; lt < 4; ++lt){
    int lg = w + lt*4;
#pragma unroll
    for (int k2 = 0; k2 < 2; ++k2)
      cfr[lt][k2] = *(const short8*)(Cm + (row0 + lg*16 + (lane & 15))*DSTATE + k2*32 + (lane >> 4)*8);
  }
  f32x4 yacc[4][4] = {};
  for (int st = 0; st < 8; ++st){
    short8 gb[2][2];
#pragma unroll
    for (int ss = 0; ss < 2; ++ss)
#pragma unroll
      for (int k2 = 0; k2 < 2; ++k2)
        gb[ss][k2] = *(const short8*)(Bm + (row0 + st*32 + ss*16 + (lane & 15))*DSTATE + k2*32 + (lane >> 4)*8);
    short8 xb[4];
#pragma unroll
    for (int pt = 0; pt < 4; ++pt)
      xb[pt] = *(const short8*)&Xt[(pt*16 + (lane & 15))*XT_P + st*32 + (lane >> 4)*8];
#pragma unroll
    for (int lt = 0; lt < 4; ++lt){
      int lg = w + lt*4;
      if (st*32 > lg*16 + 15) continue;          // s-tile fully above diagonal
#pragma unroll
      for (int ss = 0; ss < 2; ++ss){
        f32x4 g = {};
        g = __builtin_amdgcn_mfma_f32_16x16x32_bf16(cfr[lt][0], gb[ss][0], g, 0, 0, 0);
        g = __builtin_amdgcn_mfma_f32_16x16x32_bf16(cfr[lt][1], gb[ss][1], g, 0, 0, 0);
        int s = st*32 + ss*16 + (lane & 15);
        float sdAs = sdA[s];
#pragma unroll
        for (int r = 0; r < 4; ++r){
          int l = lg*16 + (lane >> 4)*4 + r;
          float m = (s <= l) ? __expf(sdA[l] - sdAs) : 0.f;
          Mw[(lt*16 + (lane >> 4)*4 + r)*M_P + ss*16 + (lane & 15)] = f2bf(g[r] * m);
        }
      }
      short8 mf = *(const short8*)&Mw[(lt*16 + (lane & 15))*M_P + (lane >> 4)*8];
#pragma unroll
      for (int pt = 0; pt < 4; ++pt)
        yacc[lt][pt] = __builtin_amdgcn_mfma_f32_16x16x32_bf16(mf, xb[pt], yacc[lt][pt], 0, 0, 0);
    }
  }
  __syncthreads();   // M dead; U becomes Ystage

  // ---- stage Y (bf16, XOR-swizzled 8-elem blocks) and write out coalesced
  unsigned short* Yst = U + w * 4096;
#pragma unroll
  for (int lt = 0; lt < 4; ++lt)
#pragma unroll
    for (int pt = 0; pt < 4; ++pt)
#pragma unroll
      for (int r = 0; r < 4; ++r){
        int row = lt*16 + (lane >> 4)*4 + r;
        int c = pt*16 + (lane & 15);
        int cs = (c & 7) | ((((c >> 3) ^ (row & 7)) & 7) << 3);
        Yst[row*64 + cs] = f2bf(yacc[lt][pt][r]);
      }
  __syncthreads();
  {
    int ltl = lane >> 4, rr = lane & 15;
    int row = ltl*16 + rr;
    int lg = (w + ltl*4)*16 + rr;
    unsigned short* dst = Yb + (row0 + lg)*DINNER + hh*DHEAD;
#pragma unroll
    for (int k = 0; k < 8; ++k){
      short8 v = *(const short8*)&Yst[row*64 + ((k ^ (row & 7)) << 3)];
      *(short8*)(dst + k*8) = v;
    }
  }
}

// ---------- sequential inter-chunk recurrence; emits bf16 prev-states ----------
__launch_bounds__(256)
__global__ void state_recur_kernel(const float* __restrict__ states, const float* __restrict__ dAcs_g,
                                   unsigned short* __restrict__ prev_bf){
  const int hh = blockIdx.x, b = blockIdx.y, t = threadIdx.x;
  float S[16];
#pragma unroll
  for (int k = 0; k < 16; ++k) S[k] = 0.f;
  for (int z = 0; z < NCHUNK; ++z){
    size_t base = (((size_t)b*NCHUNK + z)*NHEADS + hh)*(DHEAD*DSTATE);
    float cd = __expf(dAcs_g[(((size_t)(b*NHEADS + hh))*NCHUNK + z)*CHUNK + CHUNK-1]);
#pragma unroll
    for (int k = 0; k < 16; ++k){
      size_t idx = base + (size_t)k*256 + t;
      float st = states[idx];
      prev_bf[idx] = f2bf(S[k]);
      S[k] = S[k]*cd + st;
    }
  }
}

// ---------- Yo = eA * (C . prev^T) via MFMA; combine Yd + Yo + D*X ----------
// bf16 Yo staging (32KB LDS) + 4 blocks/CU.
__launch_bounds__(256, 4)
__global__ void chunk_out_kernel(const unsigned short* __restrict__ X,
                                 const unsigned short* __restrict__ Cm,
                                 const float* __restrict__ dAcs_g, const unsigned short* __restrict__ prev_bf,
                                 const float* __restrict__ Dp, unsigned short* __restrict__ Yb){
  const int z = blockIdx.x, hh = blockIdx.y, b = blockIdx.z;
  const int t = threadIdx.x, w = t >> 6, lane = t & 63;
  __shared__ __align__(16) unsigned short Yo[4][64*64];
  __shared__ float sdA[CHUNK];
  const size_t row0 = (size_t)b*LSEQ + z*CHUNK;
  sdA[t] = dAcs_g[(((size_t)(b*NHEADS + hh))*NCHUNK + z)*CHUNK + t];
  __syncthreads();
  const unsigned short* pvb = prev_bf + (((size_t)b*NCHUNK + z)*NHEADS + hh)*(DHEAD*DSTATE);
  const float Dh = Dp[hh];

  f32x4 acc[4][4] = {};
#pragma unroll
  for (int k2 = 0; k2 < 2; ++k2){
    int kc = k2*32 + (lane >> 4)*8;
    short8 a[4], bfr[4];
#pragma unroll
    for (int lt = 0; lt < 4; ++lt)
      a[lt] = *(const short8*)(Cm + (row0 + w*64 + lt*16 + (lane & 15))*DSTATE + kc);
#pragma unroll
    for (int pt = 0; pt < 4; ++pt)
      bfr[pt] = *(const short8*)(pvb + (size_t)(pt*16 + (lane & 15))*DSTATE + kc);
#pragma unroll
    for (int lt = 0; lt < 4; ++lt)
#pragma unroll
      for (int pt = 0; pt < 4; ++pt)
        acc[lt][pt] = __builtin_amdgcn_mfma_f32_16x16x32_bf16(a[lt], bfr[pt], acc[lt][pt], 0, 0, 0);
  }

  // scale rows by eA and stage (bf16, XOR-swizzled 4-elem blocks)
#pragma unroll
  for (int lt = 0; lt < 4; ++lt){
    float eA[4];
#pragma unroll
    for (int r = 0; r < 4; ++r)
      eA[r] = __expf(sdA[w*64 + lt*16 + (lane >> 4)*4 + r]);
#pragma unroll
    for (int pt = 0; pt < 4; ++pt){
      int c = pt*16 + (lane & 15);
#pragma unroll
      for (int r = 0; r < 4; ++r){
        int row = lt*16 + (lane >> 4)*4 + r;
        int blk = ((c >> 2) ^ (row & 15)) & 15;
        Yo[w][row*64 + (c & 3) + (blk << 2)] = f2bf(acc[lt][pt][r] * eA[r]);
      }
    }
  }
  __syncthreads();
  {
    int l = w*64 + lane;
    const unsigned short* xr = X + (row0 + l)*DINNER + hh*DHEAD;
    unsigned short* yr = Yb + (row0 + l)*DINNER + hh*DHEAD;
#pragma unroll
    for (int k = 0; k < 16; ++k){
      us4 v = *(const us4*)&Yo[w][lane*64 + (((k ^ (lane & 15)) & 15) << 2)];
      us4 yb = *(const us4*)(yr + k*4);
      us4 xv = *(const us4*)(xr + k*4);
      us4 o;
#pragma unroll
      for (int j = 0; j < 4; ++j)
        o[j] = f2bf(bf2f(yb[j]) + bf2f(v[j]) + Dh*bf2f(xv[j]));
      *(us4*)(yr + k*4) = o;
    }
  }
}

// ---------- gated RMSNorm: rmsnorm(y * silu(z)) * gw -> bf16 ----------
__global__ void gated_rmsnorm_kernel(const unsigned short* __restrict__ Yb,
                                     const unsigned short* __restrict__ zx,
                                     const float* __restrict__ gw, unsigned short* __restrict__ out){
  int r = blockIdx.x, t = threadIdx.x;
  float vals[8]; float s = 0.f;
#pragma unroll
  for (int i = 0; i < 8; ++i){
    int c = t + i*256;
    float y  = bf2f(Yb[(size_t)r*DINNER + c]);
    float zv = bf2f(zx[(size_t)r*DINPROJ + c]);
    float g  = y * (zv / (1.f + __expf(-zv)));
    vals[i] = g; s += g*g;
  }
  __shared__ float red[4];
  for (int off = 32; off; off >>= 1) s += __shfl_down(s, off, 64);
  if ((t & 63) == 0) red[t >> 6] = s;
  __syncthreads();
  s = red[0] + red[1] + red[2] + red[3];
  float sc = rsqrtf(s * (1.f/DINNER) + 1e-5f);
#pragma unroll
  for (int i = 0; i < 8; ++i)
    out[(size_t)r*DINNER + t + i*256] = f2bf(vals[i]*sc*gw[t + i*256]);
}

// ---------- launch ----------
extern "C" void kernel_launch(void* const* d_in, const int* in_sizes, int n_in,
                              void* d_out, int out_size, void* d_ws, size_t ws_size,
                              hipStream_t stream){
  const float* x      = (const float*)d_in[0];
  const float* in_w   = (const float*)d_in[1];
  const float* conv_w = (const float*)d_in[2];
  const float* conv_b = (const float*)d_in[3];
  const float* dt_b   = (const float*)d_in[4];
  const float* A_log  = (const float*)d_in[5];
  const float* Dp     = (const float*)d_in[6];
  const float* gnw    = (const float*)d_in[7];
  const float* out_w  = (const float*)d_in[8];
  const float* norm_w = (const float*)d_in[9];
  float* outp = (float*)d_out;

  const size_t NEEDED =
      (size_t)NROWS*DMODEL*2 + (size_t)NPAD*DMODEL*2 + (size_t)DMODEL*DINNER*2
    + (size_t)NROWS*DINPROJ*2 + (size_t)NROWS*DINNER*2 /*X*/ + (size_t)NROWS*DINNER*2 /*Yb*/
    + (size_t)NROWS*DSTATE*2*2 + (size_t)BSZ*NHEADS*LSEQ*4
    + (size_t)BSZ*NHEADS*NCHUNK*CHUNK*4
    + (size_t)BSZ*NCHUNK*NHEADS*DHEAD*DSTATE*4
    + (size_t)BSZ*NCHUNK*NHEADS*DHEAD*DSTATE*2   /* prev_bf */
    + 40*256;
  if (ws_size < NEEDED) return;   // clean fail signals ws too small

  char* p = (char*)d_ws;
  auto alloc = [&](size_t n){ char* r = p; p += (n + 255) & ~(size_t)255; return (void*)r; };
  unsigned short* h    = (unsigned short*)alloc((size_t)NROWS*DMODEL*2);
  unsigned short* wA   = (unsigned short*)alloc((size_t)NPAD*DMODEL*2);
  unsigned short* wO   = (unsigned short*)alloc((size_t)DMODEL*DINNER*2);
  unsigned short* zx   = (unsigned short*)alloc((size_t)NROWS*DINPROJ*2);
  unsigned short* X    = (unsigned short*)alloc((size_t)NROWS*DINNER*2);
  unsigned short* Yb   = (unsigned short*)alloc((size_t)NROWS*DINNER*2);
  unsigned short* Bm   = (unsigned short*)alloc((size_t)NROWS*DSTATE*2);
  unsigned short* Cm   = (unsigned short*)alloc((size_t)NROWS*DSTATE*2);
  float* dtbuf  = (float*)alloc((size_t)BSZ*NHEADS*LSEQ*4);
  float* dAcs   = (float*)alloc((size_t)BSZ*NHEADS*NCHUNK*CHUNK*4);
  float* states = (float*)alloc((size_t)BSZ*NCHUNK*NHEADS*DHEAD*DSTATE*4);
  unsigned short* prev_bf = (unsigned short*)alloc((size_t)BSZ*NCHUNK*NHEADS*DHEAD*DSTATE*2);
  unsigned short* yn = X;   // alias: X dead after chunk_out; yn born at gated_rmsnorm

  for (int layer = 0; layer < 2; ++layer){
    const float* xprev = (layer == 0) ? x : outp;
    float* xnext = outp;

    cast_pad_kernel<<<(NPAD*DMODEL + 255)/256, 256, 0, stream>>>(
        in_w + (size_t)layer*DINPROJ*DMODEL, wA, DINPROJ, DMODEL, (long long)NPAD*DMODEL);
    rmsnorm_kernel<<<NROWS, 256, 0, stream>>>(xprev, norm_w + layer*DMODEL, h);
    gemm_bt<0><<<dim3(NPAD/128, NROWS/128), 256, 0, stream>>>(
        h, wA, (void*)zx, nullptr, DMODEL, DINPROJ);
    conv_silu_kernel<<<((CONVDIM/8)*(NROWS/64) + 255)/256, 256, 0, stream>>>(
        zx, conv_w + (size_t)layer*CONVDIM*4, conv_b + layer*CONVDIM, X, Bm, Cm);
    dtscan_kernel<<<dim3(NCHUNK, NHEADS, BSZ), 256, 0, stream>>>(
        zx, dt_b + layer*NHEADS, A_log + layer*NHEADS, dtbuf, dAcs);
    chunk_main_kernel<<<dim3(NCHUNK, NHEADS, BSZ), 256, 0, stream>>>(
        X, Bm, Cm, dtbuf, dAcs, states, Yb);
    state_recur_kernel<<<dim3(NHEADS, BSZ), 256, 0, stream>>>(states, dAcs, prev_bf);
    chunk_out_kernel<<<dim3(NCHUNK, NHEADS, BSZ), 256, 0, stream>>>(
        X, Cm, dAcs, prev_bf, Dp + layer*NHEADS, Yb);
    gated_rmsnorm_kernel<<<NROWS, 256, 0, stream>>>(Yb, zx, gnw + layer*DINNER, yn);
    cast_pad_kernel<<<(DMODEL*DINNER + 255)/256, 256, 0, stream>>>(
        out_w + (size_t)layer*DMODEL*DINNER, wO, DMODEL, DINNER, (long long)DMODEL*DINNER);
    gemm_bt<1><<<dim3(DMODEL/128, NROWS/128), 256, 0, stream>>>(
        yn, wO, (void*)xnext, xprev, DINNER, DMODEL);
  }
  (void)in_sizes; (void)n_in; (void)out_size;
}

// Round 11
// 696.655 us; speedup vs baseline: 1.2385x; 1.0516x over previous
//
#include <hip/hip_runtime.h>

// ---------- constants ----------
#define DMODEL   1024
#define DINNER   2048
#define NHEADS   32
#define DHEAD    64
#define DSTATE   64
#define CONVDIM  2176
#define DINPROJ  4256
#define LSEQ     4096
#define BSZ      2
#define NCHUNK   16
#define CHUNK    256
#define NROWS    8192      // BSZ*LSEQ
#define NPAD     4352      // 34*128, padded in_proj rows
#define XT_P     264       // LDS transpose pitch (mult of 8, 2-way banks)
#define M_P      40        // M tile pitch

typedef __attribute__((ext_vector_type(8))) short  short8;
typedef __attribute__((ext_vector_type(4))) float  f32x4;
typedef __attribute__((ext_vector_type(4))) unsigned short us4;

__device__ __forceinline__ float bf2f(unsigned short u){
  return __uint_as_float(((unsigned int)u) << 16);
}
__device__ __forceinline__ unsigned short f2bf(float f){
  unsigned int i = __float_as_uint(f);
  i += 0x7fffu + ((i >> 16) & 1u);     // round-to-nearest-even
  return (unsigned short)(i >> 16);
}

// async global->LDS, 16B per lane (dest = wave-uniform base + lane*16)
__device__ __forceinline__ void gl_lds16(const void* g, void* l){
  __builtin_amdgcn_global_load_lds(
      (const __attribute__((address_space(1))) unsigned int*)g,
      (__attribute__((address_space(3))) unsigned int*)l, 16, 0, 0);
}

// ---------- cast f32 weights -> bf16 (optionally zero-pad extra rows) ----------
__global__ void cast_pad_kernel(const float* __restrict__ src, unsigned short* __restrict__ dst,
                                int rows_src, int cols, long long total){
  long long i = (long long)blockIdx.x * 256 + threadIdx.x;
  if (i >= total) return;
  long long r = i / cols;
  dst[i] = (r < rows_src) ? f2bf(src[i]) : (unsigned short)0;
}

// ---------- RMSNorm (f32 in -> bf16 out), row = 1024 ----------
__global__ void rmsnorm_kernel(const float* __restrict__ x, const float* __restrict__ w,
                               unsigned short* __restrict__ out){
  int r = blockIdx.x, t = threadIdx.x;
  const float* xr = x + (size_t)r * DMODEL;
  float v[4]; float s = 0.f;
#pragma unroll
  for (int i = 0; i < 4; ++i){ v[i] = xr[t + i*256]; s += v[i]*v[i]; }
  __shared__ float red[4];
  for (int off = 32; off; off >>= 1) s += __shfl_down(s, off, 64);
  if ((t & 63) == 0) red[t >> 6] = s;
  __syncthreads();
  s = red[0] + red[1] + red[2] + red[3];
  float sc = rsqrtf(s * (1.f/DMODEL) + 1e-5f);
#pragma unroll
  for (int i = 0; i < 4; ++i)
    out[(size_t)r*DMODEL + t + i*256] = f2bf(v[i]*sc*w[t + i*256]);
}

// ---------- bf16 MFMA GEMM, C[i,j] = sum_k A[i,k]*B[j,k] ----------
// 128x128 tile, BK=64, 4 waves (2x2). 1D grid + bijective XCD swizzle (T1).
template<int EPI>
__launch_bounds__(256, 3)
__global__ void gemm_bt(const unsigned short* __restrict__ A, const unsigned short* __restrict__ Bw,
                        void* __restrict__ Cout, const float* __restrict__ Cres,
                        int K, int Nstore, int nbx){
  __shared__ __align__(16) unsigned short As[128*64];
  __shared__ __align__(16) unsigned short Bs[128*64];
  int id = blockIdx.x;
  const int nwg = gridDim.x;
  if ((nwg & 7) == 0) id = (id & 7)*(nwg >> 3) + (id >> 3);  // bijective XCD swizzle
  const int m0 = (id / nbx) * 128, n0 = (id % nbx) * 128;
  const int t = threadIdx.x, w = t >> 6, lane = t & 63;
  const int wr = w >> 1, wc = w & 1;
  const int srow = lane >> 3;           // 0..7
  const int scol = (lane & 7) * 8;      // 0..56
  f32x4 acc[4][4] = {};

  for (int k0 = 0; k0 < K; k0 += 64){
#pragma unroll
    for (int it = 0; it < 4; ++it){
      int rr = (w*4 + it)*8 + srow;
      gl_lds16(A  + (size_t)(m0 + rr)*K + k0 + scol, &As[(w*4 + it)*512]);
      gl_lds16(Bw + (size_t)(n0 + rr)*K + k0 + scol, &Bs[(w*4 + it)*512]);
    }
    __syncthreads();
#pragma unroll
    for (int kk = 0; kk < 64; kk += 32){
      short8 af[4], bfr[4];
      int col = kk + (lane >> 4)*8;
#pragma unroll
      for (int m = 0; m < 4; ++m)
        af[m] = *(const short8*)&As[(wr*64 + m*16 + (lane & 15))*64 + col];
#pragma unroll
      for (int n = 0; n < 4; ++n)
        bfr[n] = *(const short8*)&Bs[(wc*64 + n*16 + (lane & 15))*64 + col];
#pragma unroll
      for (int m = 0; m < 4; ++m)
#pragma unroll
        for (int n = 0; n < 4; ++n)
          acc[m][n] = __builtin_amdgcn_mfma_f32_16x16x32_bf16(af[m], bfr[n], acc[m][n], 0, 0, 0);
    }
    __syncthreads();
  }

#pragma unroll
  for (int m = 0; m < 4; ++m){
#pragma unroll
    for (int n = 0; n < 4; ++n){
      int col = n0 + wc*64 + n*16 + (lane & 15);
      if (col < Nstore){
#pragma unroll
        for (int r = 0; r < 4; ++r){
          int row = m0 + wr*64 + m*16 + (lane >> 4)*4 + r;
          if (EPI == 0)
            ((unsigned short*)Cout)[(size_t)row*Nstore + col] = f2bf(acc[m][n][r]);
          else
            ((float*)Cout)[(size_t)row*Nstore + col] =
                Cres[(size_t)row*Nstore + col] + acc[m][n][r];
        }
      }
    }
  }
}

// ---------- causal conv1d (K=4) + silu, 8 channels/thread, rolling taps ----------
__global__ void conv_silu_kernel(const unsigned short* __restrict__ zx,
                                 const float* __restrict__ cw, const float* __restrict__ cb,
                                 unsigned short* __restrict__ X, unsigned short* __restrict__ Bm,
                                 unsigned short* __restrict__ Cm){
  int gid = blockIdx.x*256 + threadIdx.x;
  if (gid >= (CONVDIM/8)*(NROWS/64)) return;
  const int oc = gid % (CONVDIM/8);
  const int rb = gid / (CONVDIM/8);
  const int c = oc*8;
  const size_t r0 = (size_t)rb*64;
  const int l0 = (int)(r0 & (LSEQ-1));
  float w[4][8], bias[8];
#pragma unroll
  for (int j = 0; j < 8; ++j){
    bias[j] = cb[c+j];
#pragma unroll
    for (int i = 0; i < 4; ++i) w[i][j] = cw[(c+j)*4 + i];
  }
  const unsigned short* src = zx + DINNER + c;
  float p[3][8];
#pragma unroll
  for (int i = 0; i < 3; ++i){
    if (l0 - 3 + i >= 0){
      short8 v = *(const short8*)(src + (r0 - 3 + i)*DINPROJ);
#pragma unroll
      for (int j = 0; j < 8; ++j) p[i][j] = bf2f((unsigned short)v[j]);
    } else {
#pragma unroll
      for (int j = 0; j < 8; ++j) p[i][j] = 0.f;
    }
  }
  for (int it = 0; it < 64; ++it){
    const size_t r = r0 + it;
    short8 v = *(const short8*)(src + r*DINPROJ);
    float cur[8];
    short8 ov;
#pragma unroll
    for (int j = 0; j < 8; ++j){
      cur[j] = bf2f((unsigned short)v[j]);
      float a = bias[j] + w[0][j]*p[0][j] + w[1][j]*p[1][j] + w[2][j]*p[2][j] + w[3][j]*cur[j];
      float s = a / (1.f + __expf(-a));
      ov[j] = (short)f2bf(s);
    }
    if (c < DINNER)             *(short8*)(X  + r*DINNER + c) = ov;
    else if (c < DINNER+DSTATE) *(short8*)(Bm + r*DSTATE + (c-DINNER)) = ov;
    else                        *(short8*)(Cm + r*DSTATE + (c-DINNER-DSTATE)) = ov;
#pragma unroll
    for (int j = 0; j < 8; ++j){ p[0][j]=p[1][j]; p[1][j]=p[2][j]; p[2][j]=cur[j]; }
  }
}

// ---------- dt softplus + per-chunk inclusive cumsum of dA ----------
__global__ void dtscan_kernel(const unsigned short* __restrict__ zx, const float* __restrict__ dtb,
                              const float* __restrict__ A_log,
                              float* __restrict__ dt_sp, float* __restrict__ dAcs_g){
  const int z = blockIdx.x, hh = blockIdx.y, b = blockIdx.z;
  const int t = threadIdx.x;
  __shared__ float sdA[CHUNK];
  const float Ah = -__expf(A_log[hh]);
  size_t r = (size_t)b*LSEQ + z*CHUNK + t;
  float raw = bf2f(zx[r*DINPROJ + DINNER + CONVDIM + hh]) + dtb[hh];
  float dtv = raw > 20.f ? raw : log1pf(__expf(raw));
  sdA[t] = dtv * Ah;
  __syncthreads();
  for (int off = 1; off < CHUNK; off <<= 1){
    float v = (t >= off) ? sdA[t - off] : 0.f;
    __syncthreads();
    sdA[t] += v;
    __syncthreads();
  }
  size_t hb = (size_t)(b*NHEADS + hh);
  dt_sp[hb*LSEQ + z*CHUNK + t] = dtv;
  dAcs_g[(hb*NCHUNK + z)*CHUNK + t] = sdA[t];
}

// ---------- per-(b,chunk,head): states + within-chunk Yd, all MFMA ----------
__launch_bounds__(256, 2)
__global__ void chunk_main_kernel(const unsigned short* __restrict__ X,
                                  const unsigned short* __restrict__ Bm,
                                  const unsigned short* __restrict__ Cm,
                                  const float* __restrict__ dt_sp,
                                  const float* __restrict__ dAcs_g,
                                  float* __restrict__ states,
                                  unsigned short* __restrict__ Yb){
  const int z = blockIdx.x, hh = blockIdx.y, b = blockIdx.z;
  const int t = threadIdx.x, w = t >> 6, lane = t & 63;
  __shared__ __align__(16) unsigned short Xt[64 * XT_P];   // Xdt^T [p][l]
  __shared__ __align__(16) unsigned short U[64 * XT_P];    // union: Btdec -> M tiles -> Ystage
  __shared__ float sdA[CHUNK];
  __shared__ float sdt[CHUNK];

  const size_t row0 = (size_t)b*LSEQ + z*CHUNK;
  const size_t hb = (size_t)(b*NHEADS + hh);
  sdA[t] = dAcs_g[(hb*NCHUNK + z)*CHUNK + t];
  sdt[t] = dt_sp[hb*LSEQ + z*CHUNK + t];
  __syncthreads();
  const float total = sdA[CHUNK-1];

  // stage Xt[p][l] = X[l][p]*dt[l], U=Btdec[n][l] = B[l][n]*exp(total-sdA[l])
  for (int it = 0; it < 16; ++it){
    int l = it*16 + (t >> 4);
    int p4 = (t & 15) * 4;
    float dtl = sdt[l];
    float dec = __expf(total - sdA[l]);
    us4 xv = *(const us4*)(X  + (row0 + l)*DINNER + hh*DHEAD + p4);
    us4 bv = *(const us4*)(Bm + (row0 + l)*DSTATE + p4);
#pragma unroll
    for (int j = 0; j < 4; ++j){
      Xt[(p4 + j)*XT_P + l] = f2bf(bf2f(xv[j]) * dtl);
      U [(p4 + j)*XT_P + l] = f2bf(bf2f(bv[j]) * dec);
    }
  }
  __syncthreads();

  // ---- states: D[n][p] = sum_l Btdec[n][l] * Xt[p][l]; wave w owns n-tile w
  {
    f32x4 sacc[4] = {};
    for (int k2 = 0; k2 < 8; ++k2){
      int kc = k2*32 + (lane >> 4)*8;
      short8 a = *(const short8*)&U[(w*16 + (lane & 15))*XT_P + kc];
#pragma unroll
      for (int pt = 0; pt < 4; ++pt){
        short8 bfr = *(const short8*)&Xt[(pt*16 + (lane & 15))*XT_P + kc];
        sacc[pt] = __builtin_amdgcn_mfma_f32_16x16x32_bf16(a, bfr, sacc[pt], 0, 0, 0);
      }
    }
    float* sp = states + (((size_t)b*NCHUNK + z)*NHEADS + hh)*(DHEAD*DSTATE);
#pragma unroll
    for (int pt = 0; pt < 4; ++pt){
      int p = pt*16 + (lane & 15);
#pragma unroll
      for (int r = 0; r < 4; ++r){
        int n = w*16 + (lane >> 4)*4 + r;
        sp[p*DSTATE + n] = sacc[pt][r];
      }
    }
  }
  __syncthreads();   // Btdec dead; U becomes per-wave M tiles

  // ---- Yd: wave w owns l-tiles {w, w+4, w+8, w+12} (balanced triangle)
  unsigned short* Mw = U + w * (64 * M_P);
  short8 cfr[4][2];
#pragma unroll
  for (int lt = 0; lt < 4; ++lt){
    int lg = w + lt*4;
#pragma unroll
    for (int k2 = 0; k2 < 2; ++k2)
      cfr[lt][k2] = *(const short8*)(Cm + (row0 + lg*16 + (lane & 15))*DSTATE + k2*32 + (lane >> 4)*8);
  }
  f32x4 yacc[4][4] = {};
  for (int st = 0; st < 8; ++st){
    short8 gb[2][2];
#pragma unroll
    for (int ss = 0; ss < 2; ++ss)
#pragma unroll
      for (int k2 = 0; k2 < 2; ++k2)
        gb[ss][k2] = *(const short8*)(Bm + (row0 + st*32 + ss*16 + (lane & 15))*DSTATE + k2*32 + (lane >> 4)*8);
    short8 xb[4];
#pragma unroll
    for (int pt = 0; pt < 4; ++pt)
      xb[pt] = *(const short8*)&Xt[(pt*16 + (lane & 15))*XT_P + st*32 + (lane >> 4)*8];
#pragma unroll
    for (int lt = 0; lt < 4; ++lt){
      int lg = w + lt*4;
      if (st*32 > lg*16 + 15) continue;          // s-tile fully above diagonal
#pragma unroll
      for (int ss = 0; ss < 2; ++ss){
        f32x4 g = {};
        g = __builtin_amdgcn_mfma_f32_16x16x32_bf16(cfr[lt][0], gb[ss][0], g, 0, 0, 0);
        g = __builtin_amdgcn_mfma_f32_16x16x32_bf16(cfr[lt][1], gb[ss][1], g, 0, 0, 0);
        int s = st*32 + ss*16 + (lane & 15);
        float sdAs = sdA[s];
#pragma unroll
        for (int r = 0; r < 4; ++r){
          int l = lg*16 + (lane >> 4)*4 + r;
          float m = (s <= l) ? __expf(sdA[l] - sdAs) : 0.f;
          Mw[(lt*16 + (lane >> 4)*4 + r)*M_P + ss*16 + (lane & 15)] = f2bf(g[r] * m);
        }
      }
      short8 mf = *(const short8*)&Mw[(lt*16 + (lane & 15))*M_P + (lane >> 4)*8];
#pragma unroll
      for (int pt = 0; pt < 4; ++pt)
        yacc[lt][pt] = __builtin_amdgcn_mfma_f32_16x16x32_bf16(mf, xb[pt], yacc[lt][pt], 0, 0, 0);
    }
  }
  __syncthreads();   // M dead; U becomes Ystage

  // ---- stage Y (bf16, XOR-swizzled 8-elem blocks) and write out coalesced
  unsigned short* Yst = U + w * 4096;
#pragma unroll
  for (int lt = 0; lt < 4; ++lt)
#pragma unroll
    for (int pt = 0; pt < 4; ++pt)
#pragma unroll
      for (int r = 0; r < 4; ++r){
        int row = lt*16 + (lane >> 4)*4 + r;
        int c = pt*16 + (lane & 15);
        int cs = (c & 7) | ((((c >> 3) ^ (row & 7)) & 7) << 3);
        Yst[row*64 + cs] = f2bf(yacc[lt][pt][r]);
      }
  __syncthreads();
  {
    int ltl = lane >> 4, rr = lane & 15;
    int row = ltl*16 + rr;
    int lg = (w + ltl*4)*16 + rr;
    unsigned short* dst = Yb + (row0 + lg)*DINNER + hh*DHEAD;
#pragma unroll
    for (int k = 0; k < 8; ++k){
      short8 v = *(const short8*)&Yst[row*64 + ((k ^ (row & 7)) << 3)];
      *(short8*)(dst + k*8) = v;
    }
  }
}

// ---------- sequential inter-chunk recurrence; emits bf16 prev-states ----------
__launch_bounds__(256)
__global__ void state_recur_kernel(const float* __restrict__ states, const float* __restrict__ dAcs_g,
                                   unsigned short* __restrict__ prev_bf){
  const int hh = blockIdx.x, b = blockIdx.y, t = threadIdx.x;
  float S[16];
#pragma unroll
  for (int k = 0; k < 16; ++k) S[k] = 0.f;
  for (int z = 0; z < NCHUNK; ++z){
    size_t base = (((size_t)b*NCHUNK + z)*NHEADS + hh)*(DHEAD*DSTATE);
    float cd = __expf(dAcs_g[(((size_t)(b*NHEADS + hh))*NCHUNK + z)*CHUNK + CHUNK-1]);
#pragma unroll
    for (int k = 0; k < 16; ++k){
      size_t idx = base + (size_t)k*256 + t;
      float st = states[idx];
      prev_bf[idx] = f2bf(S[k]);
      S[k] = S[k]*cd + st;
    }
  }
}

// ---------- FUSED: Yo=eA*(C.prev^T) + Yd + D*X, gate with silu(z), RMSNorm -> yn ----------
// block = 16 rows x 2048 cols (all heads). 512 thr (8 waves x 4 heads each).
// Phase A: MFMA Yo -> LDS (bf16). Phase B: coalesced short8 pass computing
// g = (Yd+Yo+D*X)*silu(z), accumulate g^2. Phase C: row rsqrt + scaled write.
__launch_bounds__(512, 2)
__global__ void chunk_fin_kernel(const unsigned short* __restrict__ X,
                                 const unsigned short* __restrict__ Cm,
                                 const unsigned short* __restrict__ zx,
                                 const float* __restrict__ dAcs_g,
                                 const unsigned short* __restrict__ prev_bf,
                                 const float* __restrict__ Dp,
                                 const unsigned short* __restrict__ Yb,
                                 const float* __restrict__ gnw,
                                 unsigned short* __restrict__ yn){
  const int s = blockIdx.x;                 // 0..255: z*16 + slice
  const int b = blockIdx.y;
  const int z = s >> 4, sl = s & 15;
  const int t = threadIdx.x, w = t >> 6, lane = t & 63;
  const size_t row0 = (size_t)b*LSEQ + z*CHUNK + sl*16;
  __shared__ __align__(16) unsigned short Yg[16][2056];   // padded: row stride 4112B
  __shared__ float seA[NHEADS][16];
  __shared__ float sDp[NHEADS];

  { // eA table: 512 threads -> 32 heads x 16 rows
    int hh = t >> 4, r = t & 15;
    seA[hh][r] = __expf(dAcs_g[(((size_t)(b*NHEADS + hh))*NCHUNK + z)*CHUNK + sl*16 + r]);
    if (t < NHEADS) sDp[t] = Dp[t];
  }
  __syncthreads();

  // A-frags: C rows row0..row0+15 (shared across all heads)
  short8 cf[2];
#pragma unroll
  for (int k2 = 0; k2 < 2; ++k2)
    cf[k2] = *(const short8*)(Cm + (row0 + (lane & 15))*DSTATE + k2*32 + (lane >> 4)*8);

  // Phase A: per wave, 4 heads; Yo = eA * C.prev^T -> Yg
  for (int hi = 0; hi < 4; ++hi){
    int hh = w*4 + hi;
    const unsigned short* pvb = prev_bf + (((size_t)b*NCHUNK + z)*NHEADS + hh)*(DHEAD*DSTATE);
    f32x4 acc[4] = {};
#pragma unroll
    for (int k2 = 0; k2 < 2; ++k2){
      int kc = k2*32 + (lane >> 4)*8;
#pragma unroll
      for (int pt = 0; pt < 4; ++pt){
        short8 bv = *(const short8*)(pvb + (size_t)(pt*16 + (lane & 15))*DSTATE + kc);
        acc[pt] = __builtin_amdgcn_mfma_f32_16x16x32_bf16(cf[k2], bv, acc[pt], 0, 0, 0);
      }
    }
#pragma unroll
    for (int pt = 0; pt < 4; ++pt){
      int c = hh*DHEAD + pt*16 + (lane & 15);
#pragma unroll
      for (int r = 0; r < 4; ++r){
        int row = (lane >> 4)*4 + r;
        Yg[row][c] = f2bf(acc[pt][r] * seA[hh][row]);
      }
    }
  }
  __syncthreads();

  // Phase B: thread (row = t>>5, i = t&31): 8 x short8 spans of 8 cols
  const int row = t >> 5, i = t & 31;
  const size_t grow = row0 + row;
  float ss = 0.f;
#pragma unroll
  for (int j = 0; j < 8; ++j){
    int c0 = i*8 + j*256;
    short8 yo = *(const short8*)&Yg[row][c0];
    short8 yd = *(const short8*)(Yb + grow*DINNER + c0);
    short8 xv = *(const short8*)(X  + grow*DINNER + c0);
    short8 zv = *(const short8*)(zx + grow*DINPROJ + c0);
    float Dh = sDp[c0 >> 6];
    short8 og;
#pragma unroll
    for (int q = 0; q < 8; ++q){
      float y = bf2f((unsigned short)yd[q]) + bf2f((unsigned short)yo[q])
              + Dh*bf2f((unsigned short)xv[q]);
      float zf = bf2f((unsigned short)zv[q]);
      float g = y * (zf / (1.f + __expf(-zf)));
      ss += g*g;
      og[q] = (short)f2bf(g);
    }
    *(short8*)&Yg[row][c0] = og;
  }
  // reduce g^2 over the 32 threads of this row (lanes 0-31 / 32-63 are distinct rows)
  for (int off = 16; off; off >>= 1) ss += __shfl_down(ss, off, 32);
  float sc = __shfl(ss, 0, 32);
  sc = rsqrtf(sc * (1.f/DINNER) + 1e-5f);
  __syncthreads();   // Yg fully written (all waves) before... (reads are own-row only, but keep)

  // Phase C: scaled write
#pragma unroll
  for (int j = 0; j < 8; ++j){
    int c0 = i*8 + j*256;
    short8 g = *(const short8*)&Yg[row][c0];
    f32x4 w0 = *(const f32x4*)(gnw + c0);
    f32x4 w1 = *(const f32x4*)(gnw + c0 + 4);
    short8 o;
#pragma unroll
    for (int q = 0; q < 4; ++q) o[q]   = (short)f2bf(bf2f((unsigned short)g[q])  *sc*w0[q]);
#pragma unroll
    for (int q = 0; q < 4; ++q) o[q+4] = (short)f2bf(bf2f((unsigned short)g[q+4])*sc*w1[q]);
    *(short8*)(yn + grow*DINNER + c0) = o;
  }
}

// ---------- launch ----------
extern "C" void kernel_launch(void* const* d_in, const int* in_sizes, int n_in,
                              void* d_out, int out_size, void* d_ws, size_t ws_size,
                              hipStream_t stream){
  const float* x      = (const float*)d_in[0];
  const float* in_w   = (const float*)d_in[1];
  const float* conv_w = (const float*)d_in[2];
  const float* conv_b = (const float*)d_in[3];
  const float* dt_b   = (const float*)d_in[4];
  const float* A_log  = (const float*)d_in[5];
  const float* Dp     = (const float*)d_in[6];
  const float* gnw    = (const float*)d_in[7];
  const float* out_w  = (const float*)d_in[8];
  const float* norm_w = (const float*)d_in[9];
  float* outp = (float*)d_out;

  const size_t NEEDED =
      (size_t)NROWS*DMODEL*2 + (size_t)NPAD*DMODEL*2 + (size_t)DMODEL*DINNER*2
    + (size_t)NROWS*DINPROJ*2 + (size_t)NROWS*DINNER*2 /*X*/ + (size_t)NROWS*DINNER*2 /*Yb*/
    + (size_t)NROWS*DSTATE*2*2 + (size_t)BSZ*NHEADS*LSEQ*4
    + (size_t)BSZ*NHEADS*NCHUNK*CHUNK*4
    + (size_t)BSZ*NCHUNK*NHEADS*DHEAD*DSTATE*4
    + (size_t)BSZ*NCHUNK*NHEADS*DHEAD*DSTATE*2   /* prev_bf */
    + 40*256;
  if (ws_size < NEEDED) return;   // clean fail signals ws too small

  char* p = (char*)d_ws;
  auto alloc = [&](size_t n){ char* r = p; p += (n + 255) & ~(size_t)255; return (void*)r; };
  unsigned short* h    = (unsigned short*)alloc((size_t)NROWS*DMODEL*2);
  unsigned short* wA   = (unsigned short*)alloc((size_t)NPAD*DMODEL*2);
  unsigned short* wO   = (unsigned short*)alloc((size_t)DMODEL*DINNER*2);
  unsigned short* zx   = (unsigned short*)alloc((size_t)NROWS*DINPROJ*2);
  unsigned short* X    = (unsigned short*)alloc((size_t)NROWS*DINNER*2);
  unsigned short* Yb   = (unsigned short*)alloc((size_t)NROWS*DINNER*2);
  unsigned short* Bm   = (unsigned short*)alloc((size_t)NROWS*DSTATE*2);
  unsigned short* Cm   = (unsigned short*)alloc((size_t)NROWS*DSTATE*2);
  float* dtbuf  = (float*)alloc((size_t)BSZ*NHEADS*LSEQ*4);
  float* dAcs   = (float*)alloc((size_t)BSZ*NHEADS*NCHUNK*CHUNK*4);
  float* states = (float*)alloc((size_t)BSZ*NCHUNK*NHEADS*DHEAD*DSTATE*4);
  unsigned short* prev_bf = (unsigned short*)alloc((size_t)BSZ*NCHUNK*NHEADS*DHEAD*DSTATE*2);
  unsigned short* yn = X;   // alias: all X reads in chunk_fin precede yn writes (same rows)

  for (int layer = 0; layer < 2; ++layer){
    const float* xprev = (layer == 0) ? x : outp;
    float* xnext = outp;

    cast_pad_kernel<<<(NPAD*DMODEL + 255)/256, 256, 0, stream>>>(
        in_w + (size_t)layer*DINPROJ*DMODEL, wA, DINPROJ, DMODEL, (long long)NPAD*DMODEL);
    rmsnorm_kernel<<<NROWS, 256, 0, stream>>>(xprev, norm_w + layer*DMODEL, h);
    gemm_bt<0><<<dim3((NPAD/128)*(NROWS/128)), 256, 0, stream>>>(
        h, wA, (void*)zx, nullptr, DMODEL, DINPROJ, NPAD/128);
    conv_silu_kernel<<<((CONVDIM/8)*(NROWS/64) + 255)/256, 256, 0, stream>>>(
        zx, conv_w + (size_t)layer*CONVDIM*4, conv_b + layer*CONVDIM, X, Bm, Cm);
    dtscan_kernel<<<dim3(NCHUNK, NHEADS, BSZ), 256, 0, stream>>>(
        zx, dt_b + layer*NHEADS, A_log + layer*NHEADS, dtbuf, dAcs);
    chunk_main_kernel<<<dim3(NCHUNK, NHEADS, BSZ), 256, 0, stream>>>(
        X, Bm, Cm, dtbuf, dAcs, states, Yb);
    state_recur_kernel<<<dim3(NHEADS, BSZ), 256, 0, stream>>>(states, dAcs, prev_bf);
    chunk_fin_kernel<<<dim3(256, BSZ), 512, 0, stream>>>(
        X, Cm, zx, dAcs, prev_bf, Dp + layer*NHEADS, Yb, gnw + (size_t)layer*DINNER, yn);
    cast_pad_kernel<<<(DMODEL*DINNER + 255)/256, 256, 0, stream>>>(
        out_w + (size_t)layer*DMODEL*DINNER, wO, DMODEL, DINNER, (long long)DMODEL*DINNER);
    gemm_bt<1><<<dim3((DMODEL/128)*(NROWS/128)), 256, 0, stream>>>(
        yn, wO, (void*)xnext, xprev, DINNER, DMODEL, DMODEL/128);
  }
  (void)in_sizes; (void)n_in; (void)out_size;
}